// Round 1
// baseline (1834.277 us; speedup 1.0000x reference)
//
#include <hip/hip_runtime.h>
#include <hip/hip_bf16.h>
#include <math.h>

// Problem constants
#define BB 4
#define TT 1024
#define CCH 1024
#define HH 16
#define NNd 64

typedef short bf16x8 __attribute__((ext_vector_type(8)));
typedef float f32x4 __attribute__((ext_vector_type(4)));

__device__ __forceinline__ unsigned short f2bf(float f) {
  __hip_bfloat16 h = __float2bfloat16(f);
  return __builtin_bit_cast(unsigned short, h);
}
__device__ __forceinline__ float sigmoidf_(float x) { return 1.0f / (1.0f + expf(-x)); }

// ---------------------------------------------------------------------------
// Transpose + fp32->bf16 convert: in [R][Cc] fp32 -> out [Cc][R] bf16
// R, Cc multiples of 64. Grid (R/64, Cc/64), 256 threads.
// ---------------------------------------------------------------------------
__global__ __launch_bounds__(256) void transpose_bf16_kernel(
    const float* __restrict__ in, unsigned short* __restrict__ out, int R, int Cc)
{
  __shared__ unsigned short tile[64][68];
  const int r0 = blockIdx.x * 64;
  const int c0 = blockIdx.y * 64;
  const int t = threadIdx.x;
  const int rr = t >> 4;
  const int cc = (t & 15) * 4;
#pragma unroll
  for (int p = 0; p < 4; ++p) {
    int row = p * 16 + rr;
    float4 v = *(const float4*)(in + (size_t)(r0 + row) * Cc + c0 + cc);
    tile[row][cc]     = f2bf(v.x);
    tile[row][cc + 1] = f2bf(v.y);
    tile[row][cc + 2] = f2bf(v.z);
    tile[row][cc + 3] = f2bf(v.w);
  }
  __syncthreads();
#pragma unroll
  for (int p = 0; p < 4; ++p) {
    int row = p * 16 + rr;
    ushort4 o;
    o.x = tile[cc][row];
    o.y = tile[cc + 1][row];
    o.z = tile[cc + 2][row];
    o.w = tile[cc + 3][row];
    *(ushort4*)(out + (size_t)(c0 + row) * R + r0 + cc) = o;
  }
}

// ---------------------------------------------------------------------------
// Token-shift mix: xx = x[t-1]-x[t]; out_i = bf16(x + xx*coef_i) for 6 coefs.
// Grid 4096 blocks x 256 threads, 4 elements/thread.
// ---------------------------------------------------------------------------
__global__ __launch_bounds__(256) void mix_kernel(
    const float* __restrict__ x,
    const float* __restrict__ cr, const float* __restrict__ cw,
    const float* __restrict__ ck, const float* __restrict__ cv,
    const float* __restrict__ ca, const float* __restrict__ cg,
    unsigned short* __restrict__ xr, unsigned short* __restrict__ xw,
    unsigned short* __restrict__ xk, unsigned short* __restrict__ xv,
    unsigned short* __restrict__ xa, unsigned short* __restrict__ xg)
{
  const size_t idx = ((size_t)blockIdx.x * 256 + threadIdx.x) * 4;
  const int c = (int)(idx & 1023);
  const int t = (int)((idx >> 10) & 1023);
  float4 xc = *(const float4*)(x + idx);
  float4 xp = make_float4(0.f, 0.f, 0.f, 0.f);
  if (t > 0) xp = *(const float4*)(x + idx - 1024);
  float4 dx = make_float4(xp.x - xc.x, xp.y - xc.y, xp.z - xc.z, xp.w - xc.w);
  auto st = [&](unsigned short* dst, const float* coef) {
    float4 w = *(const float4*)(coef + c);
    ushort4 o;
    o.x = f2bf(fmaf(dx.x, w.x, xc.x));
    o.y = f2bf(fmaf(dx.y, w.y, xc.y));
    o.z = f2bf(fmaf(dx.z, w.z, xc.z));
    o.w = f2bf(fmaf(dx.w, w.w, xc.w));
    *(ushort4*)(dst + idx) = o;
  };
  st(xr, cr); st(xw, cw); st(xk, ck); st(xv, cv); st(xa, ca); st(xg, cg);
}

// ---------------------------------------------------------------------------
// bf16 MFMA GEMM, B given transposed (BT = [N][K], K-contiguous).
// BM=128 fixed, BN in {64,128}, BK=32 (one 16x16x32 MFMA K-step).
// EPI: 0=f32 rowmajor, 1=bf16 rowmajor, 2=bf16 tanh, 3=bf16 sigmoid,
//      4=f32 scan layout [B,H,T,N], 5=scan + f32 rowmajor dual (for v)
// ---------------------------------------------------------------------------
template<int BN, int EPI>
__global__ __launch_bounds__(256) void gemm_bt_kernel(
    const unsigned short* __restrict__ A,   // [M,K] bf16
    const unsigned short* __restrict__ BT,  // [N,K] bf16
    float* __restrict__ out,
    unsigned short* __restrict__ outb,
    float* __restrict__ out2,
    int M, int N, int K)
{
  constexpr int BM = 128, BK = 32, SK = 40;   // SK pad -> 80B rows (16B-mult)
  __shared__ __align__(16) unsigned short As[BM * SK];
  __shared__ __align__(16) unsigned short Bs[BN * SK];
  const int tid = threadIdx.x;
  const int wv = tid >> 6, lane = tid & 63;
  const int fr = lane & 15, q = lane >> 4;
  constexpr int WMS = (BN == 128) ? 2 : 4;    // waves along M
  constexpr int TM = BM / WMS / 16;           // 4 or 2
  constexpr int TN = 4;
  const int wave_m = (BN == 128) ? (wv >> 1) : wv;
  const int wave_n = (BN == 128) ? (wv & 1) : 0;
  const int m0 = blockIdx.x * BM;
  const int n0 = blockIdx.y * BN;

  f32x4 acc[TM][TN];
#pragma unroll
  for (int i = 0; i < TM; i++)
#pragma unroll
    for (int j = 0; j < TN; j++) acc[i][j] = (f32x4){0.f, 0.f, 0.f, 0.f};

  const int arow = tid >> 2;          // 0..63
  const int akc = (tid & 3) * 8;      // 0,8,16,24

  for (int k0 = 0; k0 < K; k0 += BK) {
#pragma unroll
    for (int i = 0; i < 2; ++i) {     // A: 128 rows
      int row = arow + i * 64;
      uint4 v = *(const uint4*)(A + (size_t)(m0 + row) * K + k0 + akc);
      *(uint4*)(&As[row * SK + akc]) = v;
    }
#pragma unroll
    for (int i = 0; i < BN / 64; ++i) {  // B: BN rows
      int row = arow + i * 64;
      uint4 v = *(const uint4*)(BT + (size_t)(n0 + row) * K + k0 + akc);
      *(uint4*)(&Bs[row * SK + akc]) = v;
    }
    __syncthreads();
    bf16x8 af[TM], bfv[TN];
#pragma unroll
    for (int i = 0; i < TM; i++)
      af[i] = *(const bf16x8*)(&As[(wave_m * TM * 16 + i * 16 + fr) * SK + q * 8]);
#pragma unroll
    for (int j = 0; j < TN; j++)
      bfv[j] = *(const bf16x8*)(&Bs[(wave_n * 64 + j * 16 + fr) * SK + q * 8]);
#pragma unroll
    for (int i = 0; i < TM; i++)
#pragma unroll
      for (int j = 0; j < TN; j++)
        acc[i][j] = __builtin_amdgcn_mfma_f32_16x16x32_bf16(af[i], bfv[j], acc[i][j], 0, 0, 0);
    __syncthreads();
  }

  // Epilogue. C/D layout (m89-verified): col = lane&15, row = (lane>>4)*4 + reg
#pragma unroll
  for (int i = 0; i < TM; i++) {
#pragma unroll
    for (int j = 0; j < TN; j++) {
      const int mb = m0 + wave_m * TM * 16 + i * 16 + q * 4;
      const int n = n0 + wave_n * 64 + j * 16 + fr;
#pragma unroll
      for (int r = 0; r < 4; r++) {
        const int m = mb + r;
        float val = acc[i][j][r];
        if constexpr (EPI == 0) {
          out[(size_t)m * N + n] = val;
        } else if constexpr (EPI == 1) {
          outb[(size_t)m * N + n] = f2bf(val);
        } else if constexpr (EPI == 2) {
          outb[(size_t)m * N + n] = f2bf(tanhf(val));
        } else if constexpr (EPI == 3) {
          outb[(size_t)m * N + n] = f2bf(sigmoidf_(val));
        } else {
          // scan layout: m = b*T+t (T=1024), n = h*64+nn
          const int b = m >> 10, t = m & 1023, h = n >> 6, nn = n & 63;
          const size_t sidx = ((size_t)((b << 4) + h) << 16) + ((size_t)t << 6) + nn;
          out[sidx] = val;
          if constexpr (EPI == 5) out2[(size_t)m * N + n] = val;
        }
      }
    }
  }
}

// ---------------------------------------------------------------------------
// Postproc: a = sigmoid(a0+araw); kk = normalize_per_head(k*k_k);
// aa = -kk, bb = kk*a; kmod = k*(1+(a-1)*k_a) (in-place over k_s);
// decay = exp(-e^{-1/2} * sigmoid(w0 + wraw)).
// Grid 4096 (one per (b,t)), 256 threads (4 channels each; heads = 16 threads).
// ---------------------------------------------------------------------------
__global__ __launch_bounds__(256) void postproc_kernel(
    float* __restrict__ k_s, float* __restrict__ w_s,
    float* __restrict__ aa_s, float* __restrict__ bb_s,
    const float* __restrict__ wraw, const float* __restrict__ araw,
    const float* __restrict__ w0, const float* __restrict__ a0,
    const float* __restrict__ k_k, const float* __restrict__ k_a)
{
  const int bt = blockIdx.x;
  const int b = bt >> 10, t = bt & 1023;
  const int tid = threadIdx.x;
  const int c = tid * 4;
  const int h = tid >> 4;
  const int n = c & 63;
  const size_t btc = (size_t)bt * CCH + c;
  const size_t sidx = ((size_t)((b << 4) + h) << 16) + ((size_t)t << 6) + n;

  float4 k4 = *(const float4*)(k_s + sidx);
  float4 wr4 = *(const float4*)(wraw + btc);
  float4 ar4 = *(const float4*)(araw + btc);
  float4 w04 = *(const float4*)(w0 + c);
  float4 a04 = *(const float4*)(a0 + c);
  float4 kkc = *(const float4*)(k_k + c);
  float4 ka4 = *(const float4*)(k_a + c);

  float4 a4;
  a4.x = sigmoidf_(a04.x + ar4.x);
  a4.y = sigmoidf_(a04.y + ar4.y);
  a4.z = sigmoidf_(a04.z + ar4.z);
  a4.w = sigmoidf_(a04.w + ar4.w);

  float4 kk;
  kk.x = k4.x * kkc.x; kk.y = k4.y * kkc.y; kk.z = k4.z * kkc.z; kk.w = k4.w * kkc.w;
  float ss = kk.x * kk.x + kk.y * kk.y + kk.z * kk.z + kk.w * kk.w;
  ss += __shfl_xor(ss, 1);
  ss += __shfl_xor(ss, 2);
  ss += __shfl_xor(ss, 4);
  ss += __shfl_xor(ss, 8);
  const float scale = 1.0f / fmaxf(sqrtf(ss), 1e-12f);

  float4 aa4, bb4;
  aa4.x = -kk.x * scale; bb4.x = kk.x * scale * a4.x;
  aa4.y = -kk.y * scale; bb4.y = kk.y * scale * a4.y;
  aa4.z = -kk.z * scale; bb4.z = kk.z * scale * a4.z;
  aa4.w = -kk.w * scale; bb4.w = kk.w * scale * a4.w;

  float4 km;
  km.x = k4.x * (1.0f + (a4.x - 1.0f) * ka4.x);
  km.y = k4.y * (1.0f + (a4.y - 1.0f) * ka4.y);
  km.z = k4.z * (1.0f + (a4.z - 1.0f) * ka4.z);
  km.w = k4.w * (1.0f + (a4.w - 1.0f) * ka4.w);

  const float EM = 0.60653065971263342f;  // e^{-0.5}
  float4 dw;
  dw.x = expf(-EM * sigmoidf_(w04.x + wr4.x));
  dw.y = expf(-EM * sigmoidf_(w04.y + wr4.y));
  dw.z = expf(-EM * sigmoidf_(w04.z + wr4.z));
  dw.w = expf(-EM * sigmoidf_(w04.w + wr4.w));

  *(float4*)(k_s + sidx) = km;
  *(float4*)(w_s + sidx) = dw;
  *(float4*)(aa_s + sidx) = aa4;
  *(float4*)(bb_s + sidx) = bb4;
}

// ---------------------------------------------------------------------------
// RWKV7 recurrence. One block per (b,h) [64 blocks], 256 threads = 4 waves.
// Wave w owns columns j in [16w,16w+16); lane = row i. State S[i][j] in regs.
// j-indexed per-step vectors are wave-uniform -> scalar loads (SGPR FMA ops).
// sa/out reduced across waves via LDS (2 barriers/step).
// ---------------------------------------------------------------------------
__global__ __launch_bounds__(256) void scan_kernel(
    const float* __restrict__ r_s, const float* __restrict__ w_s,
    const float* __restrict__ k_s, const float* __restrict__ v_s,
    const float* __restrict__ aa_s, const float* __restrict__ bb_s,
    float* __restrict__ o)
{
  const int bh = blockIdx.x;
  const int b = bh >> 4, h = bh & 15;
  const int lane = threadIdx.x & 63;
  const int wv = __builtin_amdgcn_readfirstlane(threadIdx.x >> 6);
  const size_t base = (size_t)bh << 16;   // (b*H+h)*T*N
  const int j0 = wv * 16;

  float S[16];
#pragma unroll
  for (int i = 0; i < 16; i++) S[i] = 0.f;

  __shared__ float sa_part[4][64];
  __shared__ float out_part[4][64];

  float* ob = o + (size_t)b * TT * CCH + h * 64;

  for (int t = 0; t < TT; ++t) {
    const size_t tb = base + ((size_t)t << 6);
    const float* ap = aa_s + tb + j0;
    const float* wp = w_s + tb + j0;
    const float* kp = k_s + tb + j0;
    const float* bp = bb_s + tb + j0;
    const float* rp = r_s + tb + j0;
    const float vi = v_s[tb + lane];

    // pass 1: partial sa_i over this wave's 16 columns
    float sp0 = 0.f, sp1 = 0.f, sp2 = 0.f, sp3 = 0.f;
#pragma unroll
    for (int jj = 0; jj < 16; jj += 4) {
      sp0 = fmaf(S[jj], ap[jj], sp0);
      sp1 = fmaf(S[jj + 1], ap[jj + 1], sp1);
      sp2 = fmaf(S[jj + 2], ap[jj + 2], sp2);
      sp3 = fmaf(S[jj + 3], ap[jj + 3], sp3);
    }
    sa_part[wv][lane] = (sp0 + sp1) + (sp2 + sp3);
    __syncthreads();
    const float sa = sa_part[0][lane] + sa_part[1][lane] + sa_part[2][lane] + sa_part[3][lane];

    // pass 2: state update + partial out
    float op0 = 0.f, op1 = 0.f, op2 = 0.f, op3 = 0.f;
#pragma unroll
    for (int jj = 0; jj < 16; jj += 4) {
      {
        float tmp = fmaf(sa, bp[jj], vi * kp[jj]);
        float s2 = fmaf(S[jj], wp[jj], tmp);
        S[jj] = s2;
        op0 = fmaf(s2, rp[jj], op0);
      }
      {
        float tmp = fmaf(sa, bp[jj + 1], vi * kp[jj + 1]);
        float s2 = fmaf(S[jj + 1], wp[jj + 1], tmp);
        S[jj + 1] = s2;
        op1 = fmaf(s2, rp[jj + 1], op1);
      }
      {
        float tmp = fmaf(sa, bp[jj + 2], vi * kp[jj + 2]);
        float s2 = fmaf(S[jj + 2], wp[jj + 2], tmp);
        S[jj + 2] = s2;
        op2 = fmaf(s2, rp[jj + 2], op2);
      }
      {
        float tmp = fmaf(sa, bp[jj + 3], vi * kp[jj + 3]);
        float s2 = fmaf(S[jj + 3], wp[jj + 3], tmp);
        S[jj + 3] = s2;
        op3 = fmaf(s2, rp[jj + 3], op3);
      }
    }
    out_part[wv][lane] = (op0 + op1) + (op2 + op3);
    __syncthreads();
    if (wv == 0) {
      ob[(size_t)t * CCH + lane] =
          out_part[0][lane] + out_part[1][lane] + out_part[2][lane] + out_part[3][lane];
    }
  }
}

// ---------------------------------------------------------------------------
// GroupNorm (H groups of N) + rwkv bonus term + *g -> bf16 for final GEMM.
// Grid 4096 (one per (b,t)), 256 threads.
// ---------------------------------------------------------------------------
__global__ __launch_bounds__(256) void gn_kernel(
    const float* __restrict__ o, const float* __restrict__ r_s,
    const float* __restrict__ k_s, const float* __restrict__ v_btc,
    const float* __restrict__ g_f, const float* __restrict__ gamma,
    const float* __restrict__ beta, const float* __restrict__ r_k,
    unsigned short* __restrict__ yg)
{
  const int bt = blockIdx.x;
  const int b = bt >> 10, t = bt & 1023;
  const int tid = threadIdx.x;
  const int c = tid * 4;
  const int h = tid >> 4;
  const int n = c & 63;
  const size_t btc = (size_t)bt * CCH + c;
  const size_t sidx = ((size_t)((b << 4) + h) << 16) + ((size_t)t << 6) + n;

  float4 o4 = *(const float4*)(o + btc);
  float4 r4 = *(const float4*)(r_s + sidx);
  float4 k4 = *(const float4*)(k_s + sidx);
  float4 v4 = *(const float4*)(v_btc + btc);
  float4 rk4 = *(const float4*)(r_k + h * 64 + n);

  float s1 = o4.x + o4.y + o4.z + o4.w;
  float s2 = o4.x * o4.x + o4.y * o4.y + o4.z * o4.z + o4.w * o4.w;
  float s3 = r4.x * k4.x * rk4.x + r4.y * k4.y * rk4.y + r4.z * k4.z * rk4.z + r4.w * k4.w * rk4.w;
#pragma unroll
  for (int m = 1; m < 16; m <<= 1) {
    s1 += __shfl_xor(s1, m);
    s2 += __shfl_xor(s2, m);
    s3 += __shfl_xor(s3, m);
  }
  const float mean = s1 * (1.0f / 64.0f);
  const float var = s2 * (1.0f / 64.0f) - mean * mean;
  const float rstd = rsqrtf(var + 0.00064f);

  float4 g4 = *(const float4*)(g_f + btc);
  float4 ga4 = *(const float4*)(gamma + c);
  float4 be4 = *(const float4*)(beta + c);

  ushort4 ov;
  ov.x = f2bf(((o4.x - mean) * rstd * ga4.x + be4.x + s3 * v4.x) * g4.x);
  ov.y = f2bf(((o4.y - mean) * rstd * ga4.y + be4.y + s3 * v4.y) * g4.y);
  ov.z = f2bf(((o4.z - mean) * rstd * ga4.z + be4.z + s3 * v4.z) * g4.z);
  ov.w = f2bf(((o4.w - mean) * rstd * ga4.w + be4.w + s3 * v4.w) * g4.w);
  *(ushort4*)(yg + btc) = ov;
}

// ---------------------------------------------------------------------------
extern "C" void kernel_launch(void* const* d_in, const int* in_sizes, int n_in,
                              void* d_out, int out_size, void* d_ws, size_t ws_size,
                              hipStream_t stream)
{
  (void)in_sizes; (void)n_in; (void)out_size;
  const float* x    = (const float*)d_in[0];
  const float* x_r  = (const float*)d_in[1];
  const float* x_w  = (const float*)d_in[2];
  const float* x_k  = (const float*)d_in[3];
  const float* x_v  = (const float*)d_in[4];
  const float* x_a  = (const float*)d_in[5];
  const float* x_g  = (const float*)d_in[6];
  const float* w0   = (const float*)d_in[7];
  const float* w1   = (const float*)d_in[8];
  const float* w2   = (const float*)d_in[9];
  const float* a0   = (const float*)d_in[10];
  const float* a1   = (const float*)d_in[11];
  const float* a2   = (const float*)d_in[12];
  // d_in[13..15] = v0,v1,v2: unused (first-layer case, v_first = v)
  const float* g1   = (const float*)d_in[16];
  const float* g2   = (const float*)d_in[17];
  const float* k_k  = (const float*)d_in[18];
  const float* k_a  = (const float*)d_in[19];
  const float* r_k  = (const float*)d_in[20];
  const float* Wr   = (const float*)d_in[21];
  const float* Wk   = (const float*)d_in[22];
  const float* Wv   = (const float*)d_in[23];
  const float* Wo   = (const float*)d_in[24];
  const float* ln_g = (const float*)d_in[25];
  const float* ln_b = (const float*)d_in[26];

  float* outp = (float*)d_out;
  float* vfirst = outp + (size_t)BB * TT * CCH;

  char* ws = (char*)d_ws;
  size_t off = 0;
  auto alloc = [&](size_t bytes) -> char* {
    char* p = ws + off;
    off += (bytes + 255) & ~(size_t)255;
    return p;
  };

  unsigned short* WrT = (unsigned short*)alloc(2097152);
  unsigned short* WkT = (unsigned short*)alloc(2097152);
  unsigned short* WvT = (unsigned short*)alloc(2097152);
  unsigned short* WoT = (unsigned short*)alloc(2097152);
  unsigned short* w1T = (unsigned short*)alloc(131072);
  unsigned short* w2T = (unsigned short*)alloc(131072);
  unsigned short* a1T = (unsigned short*)alloc(131072);
  unsigned short* a2T = (unsigned short*)alloc(131072);
  unsigned short* g1T = (unsigned short*)alloc(262144);
  unsigned short* g2T = (unsigned short*)alloc(262144);
  unsigned short* xrB = (unsigned short*)alloc(8388608);
  unsigned short* xwB = (unsigned short*)alloc(8388608);
  unsigned short* xkB = (unsigned short*)alloc(8388608);
  unsigned short* xvB = (unsigned short*)alloc(8388608);
  unsigned short* xaB = (unsigned short*)alloc(8388608);
  unsigned short* xgB = (unsigned short*)alloc(8388608);
  float* r_s  = (float*)alloc(16777216);
  float* k_s  = (float*)alloc(16777216);
  float* v_s  = (float*)alloc(16777216);
  float* w_s  = (float*)alloc(16777216);
  float* aa_s = (float*)alloc(16777216);
  float* bb_s = (float*)alloc(16777216);
  float* wraw = (float*)alloc(16777216);   // later reused as o
  float* araw = (float*)alloc(16777216);   // later reused as g
  unsigned short* hwB = (unsigned short*)alloc(524288);
  unsigned short* haB = (unsigned short*)alloc(524288);
  unsigned short* hgB = (unsigned short*)alloc(1048576);
  unsigned short* ygB = (unsigned short*)alloc(8388608);
  float* o_buf = wraw;   // wraw consumed by postproc before scan writes o
  float* g_f = araw;     // araw consumed by postproc before g-GEMM writes g

  if (off > ws_size) return;  // workspace too small: fail loudly (poisoned out)

  dim3 blk(256);

  // weight transposes (fp32 -> bf16 [N][K])
  transpose_bf16_kernel<<<dim3(16, 16), blk, 0, stream>>>(Wr, WrT, 1024, 1024);
  transpose_bf16_kernel<<<dim3(16, 16), blk, 0, stream>>>(Wk, WkT, 1024, 1024);
  transpose_bf16_kernel<<<dim3(16, 16), blk, 0, stream>>>(Wv, WvT, 1024, 1024);
  transpose_bf16_kernel<<<dim3(16, 16), blk, 0, stream>>>(Wo, WoT, 1024, 1024);
  transpose_bf16_kernel<<<dim3(16, 1), blk, 0, stream>>>(w1, w1T, 1024, 64);
  transpose_bf16_kernel<<<dim3(1, 16), blk, 0, stream>>>(w2, w2T, 64, 1024);
  transpose_bf16_kernel<<<dim3(16, 1), blk, 0, stream>>>(a1, a1T, 1024, 64);
  transpose_bf16_kernel<<<dim3(1, 16), blk, 0, stream>>>(a2, a2T, 64, 1024);
  transpose_bf16_kernel<<<dim3(16, 2), blk, 0, stream>>>(g1, g1T, 1024, 128);
  transpose_bf16_kernel<<<dim3(2, 16), blk, 0, stream>>>(g2, g2T, 128, 1024);

  // token-shift mixes -> bf16
  mix_kernel<<<4096, blk, 0, stream>>>(x, x_r, x_w, x_k, x_v, x_a, x_g,
                                       xrB, xwB, xkB, xvB, xaB, xgB);

  // big GEMMs: r, k (scan layout), v (scan layout + v_first in d_out)
  gemm_bt_kernel<128, 4><<<dim3(32, 8), blk, 0, stream>>>(xrB, WrT, r_s, nullptr, nullptr, 4096, 1024, 1024);
  gemm_bt_kernel<128, 4><<<dim3(32, 8), blk, 0, stream>>>(xkB, WkT, k_s, nullptr, nullptr, 4096, 1024, 1024);
  gemm_bt_kernel<128, 5><<<dim3(32, 8), blk, 0, stream>>>(xvB, WvT, v_s, nullptr, vfirst, 4096, 1024, 1024);

  // w-LoRA: hw = tanh(xw@w1) ; wraw = hw@w2
  gemm_bt_kernel<64, 2><<<dim3(32, 1), blk, 0, stream>>>(xwB, w1T, nullptr, hwB, nullptr, 4096, 64, 1024);
  gemm_bt_kernel<128, 0><<<dim3(32, 8), blk, 0, stream>>>(hwB, w2T, wraw, nullptr, nullptr, 4096, 1024, 64);

  // a-LoRA: ha = xa@a1 ; araw = ha@a2
  gemm_bt_kernel<64, 1><<<dim3(32, 1), blk, 0, stream>>>(xaB, a1T, nullptr, haB, nullptr, 4096, 64, 1024);
  gemm_bt_kernel<128, 0><<<dim3(32, 8), blk, 0, stream>>>(haB, a2T, araw, nullptr, nullptr, 4096, 1024, 64);

  // derive scan inputs (consumes wraw/araw; k_s -> kmod in place)
  postproc_kernel<<<4096, blk, 0, stream>>>(k_s, w_s, aa_s, bb_s, wraw, araw, w0, a0, k_k, k_a);

  // g path: hg = sigmoid(xg@g1) ; g = hg@g2 (into araw region)
  gemm_bt_kernel<128, 3><<<dim3(32, 1), blk, 0, stream>>>(xgB, g1T, nullptr, hgB, nullptr, 4096, 128, 1024);
  gemm_bt_kernel<128, 0><<<dim3(32, 8), blk, 0, stream>>>(hgB, g2T, g_f, nullptr, nullptr, 4096, 1024, 128);

  // sequential recurrence -> o (into wraw region)
  scan_kernel<<<64, blk, 0, stream>>>(r_s, w_s, k_s, v_s, aa_s, bb_s, o_buf);

  // groupnorm + rwkv bonus + *g -> bf16
  gn_kernel<<<4096, blk, 0, stream>>>(o_buf, r_s, k_s, vfirst, g_f, ln_g, ln_b, r_k, ygB);

  // final projection
  gemm_bt_kernel<128, 0><<<dim3(32, 8), blk, 0, stream>>>(ygB, WoT, outp, nullptr, nullptr, 4096, 1024, 1024);
}

// Round 2
// 1605.337 us; speedup vs baseline: 1.1426x; 1.1426x over previous
//
#include <hip/hip_runtime.h>
#include <hip/hip_bf16.h>
#include <math.h>

// Problem constants
#define BB 4
#define TT 1024
#define CCH 1024
#define HH 16
#define NNd 64

typedef short bf16x8 __attribute__((ext_vector_type(8)));
typedef float f32x4 __attribute__((ext_vector_type(4)));

__device__ __forceinline__ unsigned short f2bf(float f) {
  __hip_bfloat16 h = __float2bfloat16(f);
  return __builtin_bit_cast(unsigned short, h);
}
__device__ __forceinline__ float sigmoidf_(float x) { return 1.0f / (1.0f + expf(-x)); }

// ---------------------------------------------------------------------------
// Transpose + fp32->bf16 convert: in [R][Cc] fp32 -> out [Cc][R] bf16
// ---------------------------------------------------------------------------
__global__ __launch_bounds__(256) void transpose_bf16_kernel(
    const float* __restrict__ in, unsigned short* __restrict__ out, int R, int Cc)
{
  __shared__ unsigned short tile[64][68];
  const int r0 = blockIdx.x * 64;
  const int c0 = blockIdx.y * 64;
  const int t = threadIdx.x;
  const int rr = t >> 4;
  const int cc = (t & 15) * 4;
#pragma unroll
  for (int p = 0; p < 4; ++p) {
    int row = p * 16 + rr;
    float4 v = *(const float4*)(in + (size_t)(r0 + row) * Cc + c0 + cc);
    tile[row][cc]     = f2bf(v.x);
    tile[row][cc + 1] = f2bf(v.y);
    tile[row][cc + 2] = f2bf(v.z);
    tile[row][cc + 3] = f2bf(v.w);
  }
  __syncthreads();
#pragma unroll
  for (int p = 0; p < 4; ++p) {
    int row = p * 16 + rr;
    ushort4 o;
    o.x = tile[cc][row];
    o.y = tile[cc + 1][row];
    o.z = tile[cc + 2][row];
    o.w = tile[cc + 3][row];
    *(ushort4*)(out + (size_t)(c0 + row) * R + r0 + cc) = o;
  }
}

// ---------------------------------------------------------------------------
// Token-shift mix
// ---------------------------------------------------------------------------
__global__ __launch_bounds__(256) void mix_kernel(
    const float* __restrict__ x,
    const float* __restrict__ cr, const float* __restrict__ cw,
    const float* __restrict__ ck, const float* __restrict__ cv,
    const float* __restrict__ ca, const float* __restrict__ cg,
    unsigned short* __restrict__ xr, unsigned short* __restrict__ xw,
    unsigned short* __restrict__ xk, unsigned short* __restrict__ xv,
    unsigned short* __restrict__ xa, unsigned short* __restrict__ xg)
{
  const size_t idx = ((size_t)blockIdx.x * 256 + threadIdx.x) * 4;
  const int c = (int)(idx & 1023);
  const int t = (int)((idx >> 10) & 1023);
  float4 xc = *(const float4*)(x + idx);
  float4 xp = make_float4(0.f, 0.f, 0.f, 0.f);
  if (t > 0) xp = *(const float4*)(x + idx - 1024);
  float4 dx = make_float4(xp.x - xc.x, xp.y - xc.y, xp.z - xc.z, xp.w - xc.w);
  auto st = [&](unsigned short* dst, const float* coef) {
    float4 w = *(const float4*)(coef + c);
    ushort4 o;
    o.x = f2bf(fmaf(dx.x, w.x, xc.x));
    o.y = f2bf(fmaf(dx.y, w.y, xc.y));
    o.z = f2bf(fmaf(dx.z, w.z, xc.z));
    o.w = f2bf(fmaf(dx.w, w.w, xc.w));
    *(ushort4*)(dst + idx) = o;
  };
  st(xr, cr); st(xw, cw); st(xk, ck); st(xv, cv); st(xa, ca); st(xg, cg);
}

// ---------------------------------------------------------------------------
// bf16 MFMA GEMM, B transposed (BT = [N][K]).
// EPI: 0=f32 rowmajor, 1=bf16 rowmajor, 2=bf16 tanh, 3=bf16 sigmoid,
//      4=f32 scan layout [B,H,T,N], 5=scan + f32 rowmajor dual (for v)
// ---------------------------------------------------------------------------
template<int BN, int EPI>
__global__ __launch_bounds__(256) void gemm_bt_kernel(
    const unsigned short* __restrict__ A,
    const unsigned short* __restrict__ BT,
    float* __restrict__ out,
    unsigned short* __restrict__ outb,
    float* __restrict__ out2,
    int M, int N, int K)
{
  constexpr int BM = 128, BK = 32, SK = 40;
  __shared__ __align__(16) unsigned short As[BM * SK];
  __shared__ __align__(16) unsigned short Bs[BN * SK];
  const int tid = threadIdx.x;
  const int wv = tid >> 6, lane = tid & 63;
  const int fr = lane & 15, q = lane >> 4;
  constexpr int WMS = (BN == 128) ? 2 : 4;
  constexpr int TM = BM / WMS / 16;
  constexpr int TN = 4;
  const int wave_m = (BN == 128) ? (wv >> 1) : wv;
  const int wave_n = (BN == 128) ? (wv & 1) : 0;
  const int m0 = blockIdx.x * BM;
  const int n0 = blockIdx.y * BN;

  f32x4 acc[TM][TN];
#pragma unroll
  for (int i = 0; i < TM; i++)
#pragma unroll
    for (int j = 0; j < TN; j++) acc[i][j] = (f32x4){0.f, 0.f, 0.f, 0.f};

  const int arow = tid >> 2;
  const int akc = (tid & 3) * 8;

  for (int k0 = 0; k0 < K; k0 += BK) {
#pragma unroll
    for (int i = 0; i < 2; ++i) {
      int row = arow + i * 64;
      uint4 v = *(const uint4*)(A + (size_t)(m0 + row) * K + k0 + akc);
      *(uint4*)(&As[row * SK + akc]) = v;
    }
#pragma unroll
    for (int i = 0; i < BN / 64; ++i) {
      int row = arow + i * 64;
      uint4 v = *(const uint4*)(BT + (size_t)(n0 + row) * K + k0 + akc);
      *(uint4*)(&Bs[row * SK + akc]) = v;
    }
    __syncthreads();
    bf16x8 af[TM], bfv[TN];
#pragma unroll
    for (int i = 0; i < TM; i++)
      af[i] = *(const bf16x8*)(&As[(wave_m * TM * 16 + i * 16 + fr) * SK + q * 8]);
#pragma unroll
    for (int j = 0; j < TN; j++)
      bfv[j] = *(const bf16x8*)(&Bs[(wave_n * 64 + j * 16 + fr) * SK + q * 8]);
#pragma unroll
    for (int i = 0; i < TM; i++)
#pragma unroll
      for (int j = 0; j < TN; j++)
        acc[i][j] = __builtin_amdgcn_mfma_f32_16x16x32_bf16(af[i], bfv[j], acc[i][j], 0, 0, 0);
    __syncthreads();
  }

#pragma unroll
  for (int i = 0; i < TM; i++) {
#pragma unroll
    for (int j = 0; j < TN; j++) {
      const int mb = m0 + wave_m * TM * 16 + i * 16 + q * 4;
      const int n = n0 + wave_n * 64 + j * 16 + fr;
#pragma unroll
      for (int r = 0; r < 4; r++) {
        const int m = mb + r;
        float val = acc[i][j][r];
        if constexpr (EPI == 0) {
          out[(size_t)m * N + n] = val;
        } else if constexpr (EPI == 1) {
          outb[(size_t)m * N + n] = f2bf(val);
        } else if constexpr (EPI == 2) {
          outb[(size_t)m * N + n] = f2bf(tanhf(val));
        } else if constexpr (EPI == 3) {
          outb[(size_t)m * N + n] = f2bf(sigmoidf_(val));
        } else {
          const int b = m >> 10, t = m & 1023, h = n >> 6, nn = n & 63;
          const size_t sidx = ((size_t)((b << 4) + h) << 16) + ((size_t)t << 6) + nn;
          out[sidx] = val;
          if constexpr (EPI == 5) out2[(size_t)m * N + n] = val;
        }
      }
    }
  }
}

// ---------------------------------------------------------------------------
// Postproc: derive scan inputs (kmod in-place over k_s, decay, aa, bb)
// ---------------------------------------------------------------------------
__global__ __launch_bounds__(256) void postproc_kernel(
    float* __restrict__ k_s, float* __restrict__ w_s,
    float* __restrict__ aa_s, float* __restrict__ bb_s,
    const float* __restrict__ wraw, const float* __restrict__ araw,
    const float* __restrict__ w0, const float* __restrict__ a0,
    const float* __restrict__ k_k, const float* __restrict__ k_a)
{
  const int bt = blockIdx.x;
  const int b = bt >> 10, t = bt & 1023;
  const int tid = threadIdx.x;
  const int c = tid * 4;
  const int h = tid >> 4;
  const int n = c & 63;
  const size_t btc = (size_t)bt * CCH + c;
  const size_t sidx = ((size_t)((b << 4) + h) << 16) + ((size_t)t << 6) + n;

  float4 k4 = *(const float4*)(k_s + sidx);
  float4 wr4 = *(const float4*)(wraw + btc);
  float4 ar4 = *(const float4*)(araw + btc);
  float4 w04 = *(const float4*)(w0 + c);
  float4 a04 = *(const float4*)(a0 + c);
  float4 kkc = *(const float4*)(k_k + c);
  float4 ka4 = *(const float4*)(k_a + c);

  float4 a4;
  a4.x = sigmoidf_(a04.x + ar4.x);
  a4.y = sigmoidf_(a04.y + ar4.y);
  a4.z = sigmoidf_(a04.z + ar4.z);
  a4.w = sigmoidf_(a04.w + ar4.w);

  float4 kk;
  kk.x = k4.x * kkc.x; kk.y = k4.y * kkc.y; kk.z = k4.z * kkc.z; kk.w = k4.w * kkc.w;
  float ss = kk.x * kk.x + kk.y * kk.y + kk.z * kk.z + kk.w * kk.w;
  ss += __shfl_xor(ss, 1);
  ss += __shfl_xor(ss, 2);
  ss += __shfl_xor(ss, 4);
  ss += __shfl_xor(ss, 8);
  const float scale = 1.0f / fmaxf(sqrtf(ss), 1e-12f);

  float4 aa4, bb4;
  aa4.x = -kk.x * scale; bb4.x = kk.x * scale * a4.x;
  aa4.y = -kk.y * scale; bb4.y = kk.y * scale * a4.y;
  aa4.z = -kk.z * scale; bb4.z = kk.z * scale * a4.z;
  aa4.w = -kk.w * scale; bb4.w = kk.w * scale * a4.w;

  float4 km;
  km.x = k4.x * (1.0f + (a4.x - 1.0f) * ka4.x);
  km.y = k4.y * (1.0f + (a4.y - 1.0f) * ka4.y);
  km.z = k4.z * (1.0f + (a4.z - 1.0f) * ka4.z);
  km.w = k4.w * (1.0f + (a4.w - 1.0f) * ka4.w);

  const float EM = 0.60653065971263342f;  // e^{-0.5}
  float4 dw;
  dw.x = expf(-EM * sigmoidf_(w04.x + wr4.x));
  dw.y = expf(-EM * sigmoidf_(w04.y + wr4.y));
  dw.z = expf(-EM * sigmoidf_(w04.z + wr4.z));
  dw.w = expf(-EM * sigmoidf_(w04.w + wr4.w));

  *(float4*)(k_s + sidx) = km;
  *(float4*)(w_s + sidx) = dw;
  *(float4*)(aa_s + sidx) = aa4;
  *(float4*)(bb_s + sidx) = bb4;
}

// ---------------------------------------------------------------------------
// RWKV7 recurrence — single wave per (b,h), barrier-free.
// Rows of S are independent: lane = i holds the full row S[i][0..63] in VGPRs;
// sa_i and out_i are per-lane dot products (no cross-lane reduction).
// j-vectors (a,w,k,b,r) broadcast via LDS, pipelined:
//   global (lane-distributed, reg ring depth D) -> ds_write (1 step ahead)
//   -> uniform-address ds_read_b128 broadcasts. v_i stays in registers.
// ---------------------------------------------------------------------------
__global__ __launch_bounds__(64) void scan_kernel(
    const float* __restrict__ r_s, const float* __restrict__ w_s,
    const float* __restrict__ k_s, const float* __restrict__ v_s,
    const float* __restrict__ aa_s, const float* __restrict__ bb_s,
    float* __restrict__ o)
{
  constexpr int D = 4;
  const int bh = blockIdx.x;
  const int b = bh >> 4, h = bh & 15;
  const int lane = threadIdx.x;
  const size_t base = ((size_t)bh << 16) + lane;

  __shared__ float ring[D][5][64];   // [slot][vec: 0=aa 1=w 2=k 3=bb 4=r][j]

  float S[64];
#pragma unroll
  for (int j = 0; j < 64; ++j) S[j] = 0.f;

  float ldr[D], ldw[D], ldk[D], lda[D], ldb[D], ldv[D];
#pragma unroll
  for (int d = 0; d < D; ++d) {
    const size_t tb = base + ((size_t)d << 6);
    ldr[d] = r_s[tb]; ldw[d] = w_s[tb]; ldk[d] = k_s[tb];
    lda[d] = aa_s[tb]; ldb[d] = bb_s[tb]; ldv[d] = v_s[tb];
  }
  // prime LDS slot 0 with step 0
  ring[0][0][lane] = lda[0];
  ring[0][1][lane] = ldw[0];
  ring[0][2][lane] = ldk[0];
  ring[0][3][lane] = ldb[0];
  ring[0][4][lane] = ldr[0];

  float* op = o + (size_t)b * TT * CCH + h * 64 + lane;

  for (int tt = 0; tt < TT; tt += D) {
#pragma unroll
    for (int d = 0; d < D; ++d) {
      const int t = tt + d;
      const int dn = (d + 1) % D;
      // stage step t+1 (reg slot dn) into LDS slot dn
      ring[dn][0][lane] = lda[dn];
      ring[dn][1][lane] = ldw[dn];
      ring[dn][2][lane] = ldk[dn];
      ring[dn][3][lane] = ldb[dn];
      ring[dn][4][lane] = ldr[dn];
      const float vi = ldv[d];
      // prefetch step t+D into reg slot d (harmless tail over-read: stays in ws)
      {
        const size_t tb = base + ((size_t)(t + D) << 6);
        ldr[d] = r_s[tb]; ldw[d] = w_s[tb]; ldk[d] = k_s[tb];
        lda[d] = aa_s[tb]; ldb[d] = bb_s[tb]; ldv[d] = v_s[tb];
      }
      // pass 1: sa_i = sum_j S[i][j] * aa_j  (per-lane, 4 chains)
      float sa0 = 0.f, sa1 = 0.f, sa2 = 0.f, sa3 = 0.f;
#pragma unroll
      for (int jc = 0; jc < 16; ++jc) {
        const float4 a4 = *(const float4*)&ring[d][0][jc * 4];
        sa0 = fmaf(S[jc * 4 + 0], a4.x, sa0);
        sa1 = fmaf(S[jc * 4 + 1], a4.y, sa1);
        sa2 = fmaf(S[jc * 4 + 2], a4.z, sa2);
        sa3 = fmaf(S[jc * 4 + 3], a4.w, sa3);
      }
      const float sa = (sa0 + sa1) + (sa2 + sa3);
      // pass 2: state update + out accumulation
      float o0 = 0.f, o1 = 0.f, o2 = 0.f, o3 = 0.f;
#pragma unroll
      for (int jc = 0; jc < 16; ++jc) {
        const float4 w4 = *(const float4*)&ring[d][1][jc * 4];
        const float4 k4 = *(const float4*)&ring[d][2][jc * 4];
        const float4 b4 = *(const float4*)&ring[d][3][jc * 4];
        const float4 r4 = *(const float4*)&ring[d][4][jc * 4];
        float s0 = fmaf(S[jc * 4 + 0], w4.x, fmaf(sa, b4.x, vi * k4.x));
        S[jc * 4 + 0] = s0; o0 = fmaf(s0, r4.x, o0);
        float s1 = fmaf(S[jc * 4 + 1], w4.y, fmaf(sa, b4.y, vi * k4.y));
        S[jc * 4 + 1] = s1; o1 = fmaf(s1, r4.y, o1);
        float s2 = fmaf(S[jc * 4 + 2], w4.z, fmaf(sa, b4.z, vi * k4.z));
        S[jc * 4 + 2] = s2; o2 = fmaf(s2, r4.z, o2);
        float s3 = fmaf(S[jc * 4 + 3], w4.w, fmaf(sa, b4.w, vi * k4.w));
        S[jc * 4 + 3] = s3; o3 = fmaf(s3, r4.w, o3);
      }
      op[(size_t)t * CCH] = (o0 + o1) + (o2 + o3);
    }
  }
}

// ---------------------------------------------------------------------------
// GroupNorm + rwkv bonus + *g -> bf16
// ---------------------------------------------------------------------------
__global__ __launch_bounds__(256) void gn_kernel(
    const float* __restrict__ o, const float* __restrict__ r_s,
    const float* __restrict__ k_s, const float* __restrict__ v_btc,
    const float* __restrict__ g_f, const float* __restrict__ gamma,
    const float* __restrict__ beta, const float* __restrict__ r_k,
    unsigned short* __restrict__ yg)
{
  const int bt = blockIdx.x;
  const int b = bt >> 10, t = bt & 1023;
  const int tid = threadIdx.x;
  const int c = tid * 4;
  const int h = tid >> 4;
  const int n = c & 63;
  const size_t btc = (size_t)bt * CCH + c;
  const size_t sidx = ((size_t)((b << 4) + h) << 16) + ((size_t)t << 6) + n;

  float4 o4 = *(const float4*)(o + btc);
  float4 r4 = *(const float4*)(r_s + sidx);
  float4 k4 = *(const float4*)(k_s + sidx);
  float4 v4 = *(const float4*)(v_btc + btc);
  float4 rk4 = *(const float4*)(r_k + h * 64 + n);

  float s1 = o4.x + o4.y + o4.z + o4.w;
  float s2 = o4.x * o4.x + o4.y * o4.y + o4.z * o4.z + o4.w * o4.w;
  float s3 = r4.x * k4.x * rk4.x + r4.y * k4.y * rk4.y + r4.z * k4.z * rk4.z + r4.w * k4.w * rk4.w;
#pragma unroll
  for (int m = 1; m < 16; m <<= 1) {
    s1 += __shfl_xor(s1, m);
    s2 += __shfl_xor(s2, m);
    s3 += __shfl_xor(s3, m);
  }
  const float mean = s1 * (1.0f / 64.0f);
  const float var = s2 * (1.0f / 64.0f) - mean * mean;
  const float rstd = rsqrtf(var + 0.00064f);

  float4 g4 = *(const float4*)(g_f + btc);
  float4 ga4 = *(const float4*)(gamma + c);
  float4 be4 = *(const float4*)(beta + c);

  ushort4 ov;
  ov.x = f2bf(((o4.x - mean) * rstd * ga4.x + be4.x + s3 * v4.x) * g4.x);
  ov.y = f2bf(((o4.y - mean) * rstd * ga4.y + be4.y + s3 * v4.y) * g4.y);
  ov.z = f2bf(((o4.z - mean) * rstd * ga4.z + be4.z + s3 * v4.z) * g4.z);
  ov.w = f2bf(((o4.w - mean) * rstd * ga4.w + be4.w + s3 * v4.w) * g4.w);
  *(ushort4*)(yg + btc) = ov;
}

// ---------------------------------------------------------------------------
extern "C" void kernel_launch(void* const* d_in, const int* in_sizes, int n_in,
                              void* d_out, int out_size, void* d_ws, size_t ws_size,
                              hipStream_t stream)
{
  (void)in_sizes; (void)n_in; (void)out_size;
  const float* x    = (const float*)d_in[0];
  const float* x_r  = (const float*)d_in[1];
  const float* x_w  = (const float*)d_in[2];
  const float* x_k  = (const float*)d_in[3];
  const float* x_v  = (const float*)d_in[4];
  const float* x_a  = (const float*)d_in[5];
  const float* x_g  = (const float*)d_in[6];
  const float* w0   = (const float*)d_in[7];
  const float* w1   = (const float*)d_in[8];
  const float* w2   = (const float*)d_in[9];
  const float* a0   = (const float*)d_in[10];
  const float* a1   = (const float*)d_in[11];
  const float* a2   = (const float*)d_in[12];
  const float* g1   = (const float*)d_in[16];
  const float* g2   = (const float*)d_in[17];
  const float* k_k  = (const float*)d_in[18];
  const float* k_a  = (const float*)d_in[19];
  const float* r_k  = (const float*)d_in[20];
  const float* Wr   = (const float*)d_in[21];
  const float* Wk   = (const float*)d_in[22];
  const float* Wv   = (const float*)d_in[23];
  const float* Wo   = (const float*)d_in[24];
  const float* ln_g = (const float*)d_in[25];
  const float* ln_b = (const float*)d_in[26];

  float* outp = (float*)d_out;
  float* vfirst = outp + (size_t)BB * TT * CCH;

  char* ws = (char*)d_ws;
  size_t off = 0;
  auto alloc = [&](size_t bytes) -> char* {
    char* p = ws + off;
    off += (bytes + 255) & ~(size_t)255;
    return p;
  };

  unsigned short* WrT = (unsigned short*)alloc(2097152);
  unsigned short* WkT = (unsigned short*)alloc(2097152);
  unsigned short* WvT = (unsigned short*)alloc(2097152);
  unsigned short* WoT = (unsigned short*)alloc(2097152);
  unsigned short* w1T = (unsigned short*)alloc(131072);
  unsigned short* w2T = (unsigned short*)alloc(131072);
  unsigned short* a1T = (unsigned short*)alloc(131072);
  unsigned short* a2T = (unsigned short*)alloc(131072);
  unsigned short* g1T = (unsigned short*)alloc(262144);
  unsigned short* g2T = (unsigned short*)alloc(262144);
  unsigned short* xrB = (unsigned short*)alloc(8388608);
  unsigned short* xwB = (unsigned short*)alloc(8388608);
  unsigned short* xkB = (unsigned short*)alloc(8388608);
  unsigned short* xvB = (unsigned short*)alloc(8388608);
  unsigned short* xaB = (unsigned short*)alloc(8388608);
  unsigned short* xgB = (unsigned short*)alloc(8388608);
  float* r_s  = (float*)alloc(16777216);
  float* k_s  = (float*)alloc(16777216);
  float* v_s  = (float*)alloc(16777216);
  float* w_s  = (float*)alloc(16777216);
  float* aa_s = (float*)alloc(16777216);
  float* bb_s = (float*)alloc(16777216);
  float* wraw = (float*)alloc(16777216);   // later reused as o
  float* araw = (float*)alloc(16777216);   // later reused as g
  unsigned short* hwB = (unsigned short*)alloc(524288);
  unsigned short* haB = (unsigned short*)alloc(524288);
  unsigned short* hgB = (unsigned short*)alloc(1048576);
  unsigned short* ygB = (unsigned short*)alloc(8388608);
  float* o_buf = wraw;
  float* g_f = araw;

  if (off > ws_size) return;

  dim3 blk(256);

  transpose_bf16_kernel<<<dim3(16, 16), blk, 0, stream>>>(Wr, WrT, 1024, 1024);
  transpose_bf16_kernel<<<dim3(16, 16), blk, 0, stream>>>(Wk, WkT, 1024, 1024);
  transpose_bf16_kernel<<<dim3(16, 16), blk, 0, stream>>>(Wv, WvT, 1024, 1024);
  transpose_bf16_kernel<<<dim3(16, 16), blk, 0, stream>>>(Wo, WoT, 1024, 1024);
  transpose_bf16_kernel<<<dim3(16, 1), blk, 0, stream>>>(w1, w1T, 1024, 64);
  transpose_bf16_kernel<<<dim3(1, 16), blk, 0, stream>>>(w2, w2T, 64, 1024);
  transpose_bf16_kernel<<<dim3(16, 1), blk, 0, stream>>>(a1, a1T, 1024, 64);
  transpose_bf16_kernel<<<dim3(1, 16), blk, 0, stream>>>(a2, a2T, 64, 1024);
  transpose_bf16_kernel<<<dim3(16, 2), blk, 0, stream>>>(g1, g1T, 1024, 128);
  transpose_bf16_kernel<<<dim3(2, 16), blk, 0, stream>>>(g2, g2T, 128, 1024);

  mix_kernel<<<4096, blk, 0, stream>>>(x, x_r, x_w, x_k, x_v, x_a, x_g,
                                       xrB, xwB, xkB, xvB, xaB, xgB);

  gemm_bt_kernel<128, 4><<<dim3(32, 8), blk, 0, stream>>>(xrB, WrT, r_s, nullptr, nullptr, 4096, 1024, 1024);
  gemm_bt_kernel<128, 4><<<dim3(32, 8), blk, 0, stream>>>(xkB, WkT, k_s, nullptr, nullptr, 4096, 1024, 1024);
  gemm_bt_kernel<128, 5><<<dim3(32, 8), blk, 0, stream>>>(xvB, WvT, v_s, nullptr, vfirst, 4096, 1024, 1024);

  gemm_bt_kernel<64, 2><<<dim3(32, 1), blk, 0, stream>>>(xwB, w1T, nullptr, hwB, nullptr, 4096, 64, 1024);
  gemm_bt_kernel<128, 0><<<dim3(32, 8), blk, 0, stream>>>(hwB, w2T, wraw, nullptr, nullptr, 4096, 1024, 64);

  gemm_bt_kernel<64, 1><<<dim3(32, 1), blk, 0, stream>>>(xaB, a1T, nullptr, haB, nullptr, 4096, 64, 1024);
  gemm_bt_kernel<128, 0><<<dim3(32, 8), blk, 0, stream>>>(haB, a2T, araw, nullptr, nullptr, 4096, 1024, 64);

  postproc_kernel<<<4096, blk, 0, stream>>>(k_s, w_s, aa_s, bb_s, wraw, araw, w0, a0, k_k, k_a);

  gemm_bt_kernel<128, 3><<<dim3(32, 1), blk, 0, stream>>>(xgB, g1T, nullptr, hgB, nullptr, 4096, 128, 1024);
  gemm_bt_kernel<128, 0><<<dim3(32, 8), blk, 0, stream>>>(hgB, g2T, g_f, nullptr, nullptr, 4096, 1024, 128);

  // single-wave-per-(b,h) scan: 64 blocks x 64 threads
  scan_kernel<<<64, dim3(64), 0, stream>>>(r_s, w_s, k_s, v_s, aa_s, bb_s, o_buf);

  gn_kernel<<<4096, blk, 0, stream>>>(o_buf, r_s, k_s, vfirst, g_f, ln_g, ln_b, r_k, ygB);

  gemm_bt_kernel<128, 0><<<dim3(32, 8), blk, 0, stream>>>(ygB, WoT, outp, nullptr, nullptr, 4096, 1024, 1024);
}

// Round 3
// 702.870 us; speedup vs baseline: 2.6097x; 2.2840x over previous
//
#include <hip/hip_runtime.h>
#include <hip/hip_bf16.h>
#include <math.h>

// Problem constants
#define BB 4
#define TT 1024
#define CCH 1024
#define HH 16
#define NNd 64
#define LCH 64      // chunk length
#define NCHK 16     // chunks per sequence
#define PAD 65      // LDS row pad (floats)

typedef short bf16x8 __attribute__((ext_vector_type(8)));
typedef float f32x4 __attribute__((ext_vector_type(4)));

__device__ __forceinline__ unsigned short f2bf(float f) {
  __hip_bfloat16 h = __float2bfloat16(f);
  return __builtin_bit_cast(unsigned short, h);
}
__device__ __forceinline__ float sigmoidf_(float x) { return 1.0f / (1.0f + expf(-x)); }

// ---------------------------------------------------------------------------
// Transpose + fp32->bf16 convert: in [R][Cc] fp32 -> out [Cc][R] bf16
// ---------------------------------------------------------------------------
__global__ __launch_bounds__(256) void transpose_bf16_kernel(
    const float* __restrict__ in, unsigned short* __restrict__ out, int R, int Cc)
{
  __shared__ unsigned short tile[64][68];
  const int r0 = blockIdx.x * 64;
  const int c0 = blockIdx.y * 64;
  const int t = threadIdx.x;
  const int rr = t >> 4;
  const int cc = (t & 15) * 4;
#pragma unroll
  for (int p = 0; p < 4; ++p) {
    int row = p * 16 + rr;
    float4 v = *(const float4*)(in + (size_t)(r0 + row) * Cc + c0 + cc);
    tile[row][cc]     = f2bf(v.x);
    tile[row][cc + 1] = f2bf(v.y);
    tile[row][cc + 2] = f2bf(v.z);
    tile[row][cc + 3] = f2bf(v.w);
  }
  __syncthreads();
#pragma unroll
  for (int p = 0; p < 4; ++p) {
    int row = p * 16 + rr;
    ushort4 o;
    o.x = tile[cc][row];
    o.y = tile[cc + 1][row];
    o.z = tile[cc + 2][row];
    o.w = tile[cc + 3][row];
    *(ushort4*)(out + (size_t)(c0 + row) * R + r0 + cc) = o;
  }
}

// ---------------------------------------------------------------------------
// Token-shift mix
// ---------------------------------------------------------------------------
__global__ __launch_bounds__(256) void mix_kernel(
    const float* __restrict__ x,
    const float* __restrict__ cr, const float* __restrict__ cw,
    const float* __restrict__ ck, const float* __restrict__ cv,
    const float* __restrict__ ca, const float* __restrict__ cg,
    unsigned short* __restrict__ xr, unsigned short* __restrict__ xw,
    unsigned short* __restrict__ xk, unsigned short* __restrict__ xv,
    unsigned short* __restrict__ xa, unsigned short* __restrict__ xg)
{
  const size_t idx = ((size_t)blockIdx.x * 256 + threadIdx.x) * 4;
  const int c = (int)(idx & 1023);
  const int t = (int)((idx >> 10) & 1023);
  float4 xc = *(const float4*)(x + idx);
  float4 xp = make_float4(0.f, 0.f, 0.f, 0.f);
  if (t > 0) xp = *(const float4*)(x + idx - 1024);
  float4 dx = make_float4(xp.x - xc.x, xp.y - xc.y, xp.z - xc.z, xp.w - xc.w);
  auto st = [&](unsigned short* dst, const float* coef) {
    float4 w = *(const float4*)(coef + c);
    ushort4 o;
    o.x = f2bf(fmaf(dx.x, w.x, xc.x));
    o.y = f2bf(fmaf(dx.y, w.y, xc.y));
    o.z = f2bf(fmaf(dx.z, w.z, xc.z));
    o.w = f2bf(fmaf(dx.w, w.w, xc.w));
    *(ushort4*)(dst + idx) = o;
  };
  st(xr, cr); st(xw, cw); st(xk, ck); st(xv, cv); st(xa, ca); st(xg, cg);
}

// ---------------------------------------------------------------------------
// bf16 MFMA GEMM, B transposed (BT = [N][K]).
// EPI: 0=f32 rowmajor, 1=bf16 rowmajor, 2=bf16 tanh, 3=bf16 sigmoid,
//      4=f32 scan layout [B,H,T,N], 5=scan + f32 rowmajor dual (for v)
// ---------------------------------------------------------------------------
template<int BN, int EPI>
__global__ __launch_bounds__(256) void gemm_bt_kernel(
    const unsigned short* __restrict__ A,
    const unsigned short* __restrict__ BT,
    float* __restrict__ out,
    unsigned short* __restrict__ outb,
    float* __restrict__ out2,
    int M, int N, int K)
{
  constexpr int BM = 128, BK = 32, SK = 40;
  __shared__ __align__(16) unsigned short As[BM * SK];
  __shared__ __align__(16) unsigned short Bs[BN * SK];
  const int tid = threadIdx.x;
  const int wv = tid >> 6, lane = tid & 63;
  const int fr = lane & 15, q = lane >> 4;
  constexpr int WMS = (BN == 128) ? 2 : 4;
  constexpr int TM = BM / WMS / 16;
  constexpr int TN = 4;
  const int wave_m = (BN == 128) ? (wv >> 1) : wv;
  const int wave_n = (BN == 128) ? (wv & 1) : 0;
  const int m0 = blockIdx.x * BM;
  const int n0 = blockIdx.y * BN;

  f32x4 acc[TM][TN];
#pragma unroll
  for (int i = 0; i < TM; i++)
#pragma unroll
    for (int j = 0; j < TN; j++) acc[i][j] = (f32x4){0.f, 0.f, 0.f, 0.f};

  const int arow = tid >> 2;
  const int akc = (tid & 3) * 8;

  for (int k0 = 0; k0 < K; k0 += BK) {
#pragma unroll
    for (int i = 0; i < 2; ++i) {
      int row = arow + i * 64;
      uint4 v = *(const uint4*)(A + (size_t)(m0 + row) * K + k0 + akc);
      *(uint4*)(&As[row * SK + akc]) = v;
    }
#pragma unroll
    for (int i = 0; i < BN / 64; ++i) {
      int row = arow + i * 64;
      uint4 v = *(const uint4*)(BT + (size_t)(n0 + row) * K + k0 + akc);
      *(uint4*)(&Bs[row * SK + akc]) = v;
    }
    __syncthreads();
    bf16x8 af[TM], bfv[TN];
#pragma unroll
    for (int i = 0; i < TM; i++)
      af[i] = *(const bf16x8*)(&As[(wave_m * TM * 16 + i * 16 + fr) * SK + q * 8]);
#pragma unroll
    for (int j = 0; j < TN; j++)
      bfv[j] = *(const bf16x8*)(&Bs[(wave_n * 64 + j * 16 + fr) * SK + q * 8]);
#pragma unroll
    for (int i = 0; i < TM; i++)
#pragma unroll
      for (int j = 0; j < TN; j++)
        acc[i][j] = __builtin_amdgcn_mfma_f32_16x16x32_bf16(af[i], bfv[j], acc[i][j], 0, 0, 0);
    __syncthreads();
  }

#pragma unroll
  for (int i = 0; i < TM; i++) {
#pragma unroll
    for (int j = 0; j < TN; j++) {
      const int mb = m0 + wave_m * TM * 16 + i * 16 + q * 4;
      const int n = n0 + wave_n * 64 + j * 16 + fr;
#pragma unroll
      for (int r = 0; r < 4; r++) {
        const int m = mb + r;
        float val = acc[i][j][r];
        if constexpr (EPI == 0) {
          out[(size_t)m * N + n] = val;
        } else if constexpr (EPI == 1) {
          outb[(size_t)m * N + n] = f2bf(val);
        } else if constexpr (EPI == 2) {
          outb[(size_t)m * N + n] = f2bf(tanhf(val));
        } else if constexpr (EPI == 3) {
          outb[(size_t)m * N + n] = f2bf(sigmoidf_(val));
        } else {
          const int b = m >> 10, t = m & 1023, h = n >> 6, nn = n & 63;
          const size_t sidx = ((size_t)((b << 4) + h) << 16) + ((size_t)t << 6) + nn;
          out[sidx] = val;
          if constexpr (EPI == 5) out2[(size_t)m * N + n] = val;
        }
      }
    }
  }
}

// ---------------------------------------------------------------------------
// Postproc: a = sigmoid(a0+araw); kk = normalize(k*k_k); aa=-kk, bb=kk*a;
// kmod in-place; lw = log decay = -e^{-0.5} * sigmoid(w0+wraw)  (LOG, no exp)
// ---------------------------------------------------------------------------
__global__ __launch_bounds__(256) void postproc_kernel(
    float* __restrict__ k_s, float* __restrict__ lw_s,
    float* __restrict__ aa_s, float* __restrict__ bb_s,
    const float* __restrict__ wraw, const float* __restrict__ araw,
    const float* __restrict__ w0, const float* __restrict__ a0,
    const float* __restrict__ k_k, const float* __restrict__ k_a)
{
  const int bt = blockIdx.x;
  const int b = bt >> 10, t = bt & 1023;
  const int tid = threadIdx.x;
  const int c = tid * 4;
  const int h = tid >> 4;
  const int n = c & 63;
  const size_t btc = (size_t)bt * CCH + c;
  const size_t sidx = ((size_t)((b << 4) + h) << 16) + ((size_t)t << 6) + n;

  float4 k4 = *(const float4*)(k_s + sidx);
  float4 wr4 = *(const float4*)(wraw + btc);
  float4 ar4 = *(const float4*)(araw + btc);
  float4 w04 = *(const float4*)(w0 + c);
  float4 a04 = *(const float4*)(a0 + c);
  float4 kkc = *(const float4*)(k_k + c);
  float4 ka4 = *(const float4*)(k_a + c);

  float4 a4;
  a4.x = sigmoidf_(a04.x + ar4.x);
  a4.y = sigmoidf_(a04.y + ar4.y);
  a4.z = sigmoidf_(a04.z + ar4.z);
  a4.w = sigmoidf_(a04.w + ar4.w);

  float4 kk;
  kk.x = k4.x * kkc.x; kk.y = k4.y * kkc.y; kk.z = k4.z * kkc.z; kk.w = k4.w * kkc.w;
  float ss = kk.x * kk.x + kk.y * kk.y + kk.z * kk.z + kk.w * kk.w;
  ss += __shfl_xor(ss, 1);
  ss += __shfl_xor(ss, 2);
  ss += __shfl_xor(ss, 4);
  ss += __shfl_xor(ss, 8);
  const float scale = 1.0f / fmaxf(sqrtf(ss), 1e-12f);

  float4 aa4, bb4;
  aa4.x = -kk.x * scale; bb4.x = kk.x * scale * a4.x;
  aa4.y = -kk.y * scale; bb4.y = kk.y * scale * a4.y;
  aa4.z = -kk.z * scale; bb4.z = kk.z * scale * a4.z;
  aa4.w = -kk.w * scale; bb4.w = kk.w * scale * a4.w;

  float4 km;
  km.x = k4.x * (1.0f + (a4.x - 1.0f) * ka4.x);
  km.y = k4.y * (1.0f + (a4.y - 1.0f) * ka4.y);
  km.z = k4.z * (1.0f + (a4.z - 1.0f) * ka4.z);
  km.w = k4.w * (1.0f + (a4.w - 1.0f) * ka4.w);

  const float EM = 0.60653065971263342f;  // e^{-0.5}
  float4 lw;
  lw.x = -EM * sigmoidf_(w04.x + wr4.x);
  lw.y = -EM * sigmoidf_(w04.y + wr4.y);
  lw.z = -EM * sigmoidf_(w04.z + wr4.z);
  lw.w = -EM * sigmoidf_(w04.w + wr4.w);

  *(float4*)(k_s + sidx) = km;
  *(float4*)(lw_s + sidx) = lw;
  *(float4*)(aa_s + sidx) = aa4;
  *(float4*)(bb_s + sidx) = bb4;
}

// ---------------------------------------------------------------------------
// Phase 1: per-(bh,chunk) chunked-DPLR operators.
// Recurrence: S_t = S_{t-1} diag(e^{lw_t}) + (S_{t-1} a_t) b_t^T + v_t k_t^T
// With ST = S^T (key x value):
//   ST' = Mc ST + Ncc,  Out = Pc ST + Oloc   (per chunk)
// Mc = diag(e^{gL}) + Btil^T AhT ; Ncc = Btil^T Qloc + Ktil^T V
// Pc = Rhat + DBR AhT            ; Oloc = DBR Qloc + DKR V
// where g = cumsum(lw), Ahat=a*e^{g[t-1]}, Bp=b*e^{-g}, Kp=k*e^{-g},
// Rhat=r*e^{g}, Btil=Bp*e^{gL}, Ktil=Kp*e^{gL},
// LBA=strictlow(Ahat Bp^T), LKA=strictlow(Ahat Kp^T),
// DBR=low(Rhat Bp^T), DKR=low(Rhat Kp^T),
// [AhT|Y] = (I-LBA)^{-1} [Ahat|LKA], Qloc = Y V.
// ---------------------------------------------------------------------------
__global__ __launch_bounds__(256, 1) void chunk_ops_kernel(
    const float* __restrict__ r_s, const float* __restrict__ lw_s,
    const float* __restrict__ k_s, const float* __restrict__ v_s,
    const float* __restrict__ aa_s, const float* __restrict__ bb_s,
    float* __restrict__ McG, float* __restrict__ NcG,
    float* __restrict__ PcG, float* __restrict__ OlG)
{
  extern __shared__ float sm[];
  float* AH = sm;                  // Ahat -> AhT
  float* BP = sm + 1 * 4160;       // Bp -> Btil
  float* KP = sm + 2 * 4160;       // Kp -> Ktil
  float* RH = sm + 3 * 4160;       // Rhat
  float* VS = sm + 4 * 4160;       // V
  float* LB = sm + 5 * 4160;       // LBA
  float* LK = sm + 6 * 4160;       // LKA -> Y -> Qloc
  float* DB = sm + 7 * 4160;       // DBR
  float* DK = sm + 8 * 4160;       // DKR
  float* GL = sm + 9 * 4160;       // [64] g at t=63
  float* SS = sm + 9 * 4160 + 64;  // [4][64] strip sums

  const int inst = blockIdx.x;
  const int bh = inst >> 4, c = inst & 15;
  const size_t cb = ((size_t)bh << 16) + ((size_t)c << 12);
  const int tid = threadIdx.x;
  const int j = tid & 63, p = tid >> 6;

  // ---- log-decay cumsum (column j, strip p) ----
  float g[16];
  {
    float run = 0.f;
#pragma unroll
    for (int u = 0; u < 16; ++u) {
      run += lw_s[cb + (size_t)(16 * p + u) * 64 + j];
      g[u] = run;
    }
    SS[p * 64 + j] = run;
  }
  __syncthreads();
  float goff = 0.f;
  for (int q = 0; q < p; ++q) goff += SS[q * 64 + j];
#pragma unroll
  for (int u = 0; u < 16; ++u) g[u] += goff;
  if (p == 3) GL[j] = g[15];

  // ---- build transformed matrices ----
#pragma unroll
  for (int u = 0; u < 16; ++u) {
    const int t = 16 * p + u;
    const size_t gi = cb + (size_t)t * 64 + j;
    const float gm1 = (u == 0) ? goff : g[u - 1];
    AH[t * PAD + j] = aa_s[gi] * expf(gm1);
    const float em = expf(-g[u]);
    BP[t * PAD + j] = bb_s[gi] * em;
    KP[t * PAD + j] = k_s[gi] * em;
    RH[t * PAD + j] = r_s[gi] * expf(g[u]);
    VS[t * PAD + j] = v_s[gi];
  }
  __syncthreads();

  const int tt = tid >> 4, s4 = tid & 15;

  // ---- G1+G2: LBA / LKA (strict lower) ----
  {
    float aB[4][4] = {{0}}, aK[4][4] = {{0}};
#pragma unroll 4
    for (int jj = 0; jj < 64; ++jj) {
      float av[4], bv[4], kv[4];
#pragma unroll
      for (int u = 0; u < 4; ++u) av[u] = AH[(4 * tt + u) * PAD + jj];
#pragma unroll
      for (int v = 0; v < 4; ++v) { bv[v] = BP[(4 * s4 + v) * PAD + jj]; kv[v] = KP[(4 * s4 + v) * PAD + jj]; }
#pragma unroll
      for (int u = 0; u < 4; ++u)
#pragma unroll
        for (int v = 0; v < 4; ++v) {
          aB[u][v] = fmaf(av[u], bv[v], aB[u][v]);
          aK[u][v] = fmaf(av[u], kv[v], aK[u][v]);
        }
    }
#pragma unroll
    for (int u = 0; u < 4; ++u)
#pragma unroll
      for (int v = 0; v < 4; ++v) {
        const int t = 4 * tt + u, s = 4 * s4 + v;
        LB[t * PAD + s] = (s < t) ? aB[u][v] : 0.f;
        LK[t * PAD + s] = (s < t) ? aK[u][v] : 0.f;
      }
  }
  // ---- G3+G4: DBR / DKR (lower incl diag) ----
  {
    float aB[4][4] = {{0}}, aK[4][4] = {{0}};
#pragma unroll 4
    for (int jj = 0; jj < 64; ++jj) {
      float rv[4], bv[4], kv[4];
#pragma unroll
      for (int u = 0; u < 4; ++u) rv[u] = RH[(4 * tt + u) * PAD + jj];
#pragma unroll
      for (int v = 0; v < 4; ++v) { bv[v] = BP[(4 * s4 + v) * PAD + jj]; kv[v] = KP[(4 * s4 + v) * PAD + jj]; }
#pragma unroll
      for (int u = 0; u < 4; ++u)
#pragma unroll
        for (int v = 0; v < 4; ++v) {
          aB[u][v] = fmaf(rv[u], bv[v], aB[u][v]);
          aK[u][v] = fmaf(rv[u], kv[v], aK[u][v]);
        }
    }
#pragma unroll
    for (int u = 0; u < 4; ++u)
#pragma unroll
      for (int v = 0; v < 4; ++v) {
        const int t = 4 * tt + u, s = 4 * s4 + v;
        DB[t * PAD + s] = (s <= t) ? aB[u][v] : 0.f;
        DK[t * PAD + s] = (s <= t) ? aK[u][v] : 0.f;
      }
  }
  __syncthreads();

  // ---- scale Bp->Btil, Kp->Ktil ----
  {
    const float egl = expf(GL[j]);
#pragma unroll
    for (int u = 0; u < 16; ++u) {
      const int t = 16 * p + u;
      BP[t * PAD + j] *= egl;
      KP[t * PAD + j] *= egl;
    }
  }
  __syncthreads();

  // ---- triangular solve (I-LBA) X = [Ahat | LKA], in place, per column ----
  if (tid < 128) {
    float* X = (tid < 64) ? AH : LK;
    const int jc = tid & 63;
    float x[64];
#pragma unroll
    for (int t = 0; t < 64; ++t) x[t] = X[t * PAD + jc];
#pragma unroll
    for (int t = 1; t < 64; ++t) {
      float a0 = 0.f, a1 = 0.f;
#pragma unroll
      for (int s = 0; s + 1 < t; s += 2) {
        a0 = fmaf(LB[t * PAD + s], x[s], a0);
        a1 = fmaf(LB[t * PAD + s + 1], x[s + 1], a1);
      }
      if (t & 1) a0 = fmaf(LB[t * PAD + (t - 1)], x[t - 1], a0);
      x[t] += a0 + a1;
    }
#pragma unroll
    for (int t = 0; t < 64; ++t) X[t * PAD + jc] = x[t];
  }
  __syncthreads();

  // ---- Qloc = Y V  (Y in LK slot; reg-buffer then overwrite LK) ----
  {
    float acc[4][4] = {{0}};
#pragma unroll 4
    for (int s = 0; s < 64; ++s) {
      float yv[4], vv[4];
#pragma unroll
      for (int u = 0; u < 4; ++u) yv[u] = LK[(4 * tt + u) * PAD + s];
#pragma unroll
      for (int v = 0; v < 4; ++v) vv[v] = VS[s * PAD + 4 * s4 + v];
#pragma unroll
      for (int u = 0; u < 4; ++u)
#pragma unroll
        for (int v = 0; v < 4; ++v) acc[u][v] = fmaf(yv[u], vv[v], acc[u][v]);
    }
    __syncthreads();
#pragma unroll
    for (int u = 0; u < 4; ++u)
#pragma unroll
      for (int v = 0; v < 4; ++v) LK[(4 * tt + u) * PAD + 4 * s4 + v] = acc[u][v];
  }
  __syncthreads();

  const size_t ob = (size_t)inst * 4096;

  // ---- Mc = diag(e^gL) + Btil^T AhT ; Ncc = Btil^T Qloc + Ktil^T V ----
  {
    float mAcc[4][4] = {{0}}, nAcc[4][4] = {{0}};
#pragma unroll 4
    for (int t = 0; t < 64; ++t) {
      float bt[4], kt[4], at[4], qt[4], vt[4];
#pragma unroll
      for (int u = 0; u < 4; ++u) { bt[u] = BP[t * PAD + 4 * tt + u]; kt[u] = KP[t * PAD + 4 * tt + u]; }
#pragma unroll
      for (int v = 0; v < 4; ++v) {
        at[v] = AH[t * PAD + 4 * s4 + v];
        qt[v] = LK[t * PAD + 4 * s4 + v];
        vt[v] = VS[t * PAD + 4 * s4 + v];
      }
#pragma unroll
      for (int u = 0; u < 4; ++u)
#pragma unroll
        for (int v = 0; v < 4; ++v) {
          mAcc[u][v] = fmaf(bt[u], at[v], mAcc[u][v]);
          nAcc[u][v] = fmaf(bt[u], qt[v], fmaf(kt[u], vt[v], nAcc[u][v]));
        }
    }
#pragma unroll
    for (int u = 0; u < 4; ++u) {
      const int i = 4 * tt + u;
#pragma unroll
      for (int v = 0; v < 4; ++v)
        if (i == 4 * s4 + v) mAcc[u][v] += expf(GL[i]);
      float4 m4 = make_float4(mAcc[u][0], mAcc[u][1], mAcc[u][2], mAcc[u][3]);
      float4 n4 = make_float4(nAcc[u][0], nAcc[u][1], nAcc[u][2], nAcc[u][3]);
      *(float4*)(McG + ob + (size_t)i * 64 + 4 * s4) = m4;
      *(float4*)(NcG + ob + (size_t)i * 64 + 4 * s4) = n4;
    }
  }

  // ---- Pc = Rhat + DBR AhT ; Oloc = DBR Qloc + DKR V ----
  {
    float pAcc[4][4] = {{0}}, oAcc[4][4] = {{0}};
#pragma unroll 4
    for (int s = 0; s < 64; ++s) {
      float dv[4], ev[4], av[4], qv[4], vv[4];
#pragma unroll
      for (int u = 0; u < 4; ++u) { dv[u] = DB[(4 * tt + u) * PAD + s]; ev[u] = DK[(4 * tt + u) * PAD + s]; }
#pragma unroll
      for (int v = 0; v < 4; ++v) {
        av[v] = AH[s * PAD + 4 * s4 + v];
        qv[v] = LK[s * PAD + 4 * s4 + v];
        vv[v] = VS[s * PAD + 4 * s4 + v];
      }
#pragma unroll
      for (int u = 0; u < 4; ++u)
#pragma unroll
        for (int v = 0; v < 4; ++v) {
          pAcc[u][v] = fmaf(dv[u], av[v], pAcc[u][v]);
          oAcc[u][v] = fmaf(dv[u], qv[v], fmaf(ev[u], vv[v], oAcc[u][v]));
        }
    }
#pragma unroll
    for (int u = 0; u < 4; ++u) {
      const int t = 4 * tt + u;
#pragma unroll
      for (int v = 0; v < 4; ++v) pAcc[u][v] += RH[t * PAD + 4 * s4 + v];
      float4 p4 = make_float4(pAcc[u][0], pAcc[u][1], pAcc[u][2], pAcc[u][3]);
      float4 o4 = make_float4(oAcc[u][0], oAcc[u][1], oAcc[u][2], oAcc[u][3]);
      *(float4*)(PcG + ob + (size_t)t * 64 + 4 * s4) = p4;
      *(float4*)(OlG + ob + (size_t)t * 64 + 4 * s4) = o4;
    }
  }
}

// ---------------------------------------------------------------------------
// Phase 2: sequential chunk-state propagation per (b,h): ST' = Mc ST + Ncc.
// Saves ST (chunk-entry state) per chunk for phase 3.
// ---------------------------------------------------------------------------
__global__ __launch_bounds__(256) void chunk_scan_kernel(
    const float* __restrict__ McG, const float* __restrict__ NcG,
    float* __restrict__ Sch)
{
  __shared__ float ST[64 * PAD];
  __shared__ float MB[64 * PAD];
  const int bh = blockIdx.x;
  const int tid = threadIdx.x;
  const int it = tid >> 4, jt = tid & 15;

#pragma unroll
  for (int q = 0; q < 16; ++q) {
    int idx = q * 256 + tid;
    ST[(idx >> 6) * PAD + (idx & 63)] = 0.f;
  }
  __syncthreads();

  for (int c = 0; c < 16; ++c) {
    const size_t ob = ((((size_t)bh << 4) + c) << 12);
#pragma unroll
    for (int q = 0; q < 4; ++q) {
      int idx = q * 1024 + tid * 4;
      int row = idx >> 6, col = idx & 63;
      float4 sv = make_float4(ST[row * PAD + col], ST[row * PAD + col + 1],
                              ST[row * PAD + col + 2], ST[row * PAD + col + 3]);
      *(float4*)(Sch + ob + idx) = sv;
      float4 mv = *(const float4*)(McG + ob + idx);
      MB[row * PAD + col] = mv.x; MB[row * PAD + col + 1] = mv.y;
      MB[row * PAD + col + 2] = mv.z; MB[row * PAD + col + 3] = mv.w;
    }
    __syncthreads();
    float acc[4][4];
#pragma unroll
    for (int u = 0; u < 4; ++u) {
      float4 n4 = *(const float4*)(NcG + ob + (size_t)(4 * it + u) * 64 + 4 * jt);
      acc[u][0] = n4.x; acc[u][1] = n4.y; acc[u][2] = n4.z; acc[u][3] = n4.w;
    }
#pragma unroll 4
    for (int pp = 0; pp < 64; ++pp) {
      float mv[4], sv[4];
#pragma unroll
      for (int u = 0; u < 4; ++u) mv[u] = MB[(4 * it + u) * PAD + pp];
#pragma unroll
      for (int v = 0; v < 4; ++v) sv[v] = ST[pp * PAD + 4 * jt + v];
#pragma unroll
      for (int u = 0; u < 4; ++u)
#pragma unroll
        for (int v = 0; v < 4; ++v) acc[u][v] = fmaf(mv[u], sv[v], acc[u][v]);
    }
    __syncthreads();
#pragma unroll
    for (int u = 0; u < 4; ++u)
#pragma unroll
      for (int v = 0; v < 4; ++v) ST[(4 * it + u) * PAD + 4 * jt + v] = acc[u][v];
    __syncthreads();
  }
}

// ---------------------------------------------------------------------------
// Phase 3: Out = Pc ST + Oloc -> o[b][t][h*64+j]
// ---------------------------------------------------------------------------
__global__ __launch_bounds__(256) void chunk_out_kernel(
    const float* __restrict__ PcG, const float* __restrict__ OlG,
    const float* __restrict__ Sch, float* __restrict__ o)
{
  __shared__ float ST[64 * PAD];
  __shared__ float PB[64 * PAD];
  const int inst = blockIdx.x;
  const int bh = inst >> 4, c = inst & 15;
  const int b = bh >> 4, h = bh & 15;
  const int tid = threadIdx.x;
  const int tt = tid >> 4, jt = tid & 15;
  const size_t ob = (size_t)inst << 12;

#pragma unroll
  for (int q = 0; q < 4; ++q) {
    int idx = q * 1024 + tid * 4;
    int row = idx >> 6, col = idx & 63;
    float4 sv = *(const float4*)(Sch + ob + idx);
    ST[row * PAD + col] = sv.x; ST[row * PAD + col + 1] = sv.y;
    ST[row * PAD + col + 2] = sv.z; ST[row * PAD + col + 3] = sv.w;
    float4 pv = *(const float4*)(PcG + ob + idx);
    PB[row * PAD + col] = pv.x; PB[row * PAD + col + 1] = pv.y;
    PB[row * PAD + col + 2] = pv.z; PB[row * PAD + col + 3] = pv.w;
  }
  __syncthreads();

  float acc[4][4];
#pragma unroll
  for (int u = 0; u < 4; ++u) {
    float4 o4 = *(const float4*)(OlG + ob + (size_t)(4 * tt + u) * 64 + 4 * jt);
    acc[u][0] = o4.x; acc[u][1] = o4.y; acc[u][2] = o4.z; acc[u][3] = o4.w;
  }
#pragma unroll 4
  for (int pp = 0; pp < 64; ++pp) {
    float pv[4], sv[4];
#pragma unroll
    for (int u = 0; u < 4; ++u) pv[u] = PB[(4 * tt + u) * PAD + pp];
#pragma unroll
    for (int v = 0; v < 4; ++v) sv[v] = ST[pp * PAD + 4 * jt + v];
#pragma unroll
    for (int u = 0; u < 4; ++u)
#pragma unroll
      for (int v = 0; v < 4; ++v) acc[u][v] = fmaf(pv[u], sv[v], acc[u][v]);
  }
#pragma unroll
  for (int u = 0; u < 4; ++u) {
    const int tg = c * 64 + 4 * tt + u;
    float4 o4 = make_float4(acc[u][0], acc[u][1], acc[u][2], acc[u][3]);
    *(float4*)(o + ((size_t)b * 1024 + tg) * 1024 + h * 64 + 4 * jt) = o4;
  }
}

// ---------------------------------------------------------------------------
// GroupNorm + rwkv bonus + *g -> bf16
// ---------------------------------------------------------------------------
__global__ __launch_bounds__(256) void gn_kernel(
    const float* __restrict__ o, const float* __restrict__ r_s,
    const float* __restrict__ k_s, const float* __restrict__ v_btc,
    const float* __restrict__ g_f, const float* __restrict__ gamma,
    const float* __restrict__ beta, const float* __restrict__ r_k,
    unsigned short* __restrict__ yg)
{
  const int bt = blockIdx.x;
  const int b = bt >> 10, t = bt & 1023;
  const int tid = threadIdx.x;
  const int c = tid * 4;
  const int h = tid >> 4;
  const int n = c & 63;
  const size_t btc = (size_t)bt * CCH + c;
  const size_t sidx = ((size_t)((b << 4) + h) << 16) + ((size_t)t << 6) + n;

  float4 o4 = *(const float4*)(o + btc);
  float4 r4 = *(const float4*)(r_s + sidx);
  float4 k4 = *(const float4*)(k_s + sidx);
  float4 v4 = *(const float4*)(v_btc + btc);
  float4 rk4 = *(const float4*)(r_k + h * 64 + n);

  float s1 = o4.x + o4.y + o4.z + o4.w;
  float s2 = o4.x * o4.x + o4.y * o4.y + o4.z * o4.z + o4.w * o4.w;
  float s3 = r4.x * k4.x * rk4.x + r4.y * k4.y * rk4.y + r4.z * k4.z * rk4.z + r4.w * k4.w * rk4.w;
#pragma unroll
  for (int m = 1; m < 16; m <<= 1) {
    s1 += __shfl_xor(s1, m);
    s2 += __shfl_xor(s2, m);
    s3 += __shfl_xor(s3, m);
  }
  const float mean = s1 * (1.0f / 64.0f);
  const float var = s2 * (1.0f / 64.0f) - mean * mean;
  const float rstd = rsqrtf(var + 0.00064f);

  float4 g4 = *(const float4*)(g_f + btc);
  float4 ga4 = *(const float4*)(gamma + c);
  float4 be4 = *(const float4*)(beta + c);

  ushort4 ov;
  ov.x = f2bf(((o4.x - mean) * rstd * ga4.x + be4.x + s3 * v4.x) * g4.x);
  ov.y = f2bf(((o4.y - mean) * rstd * ga4.y + be4.y + s3 * v4.y) * g4.y);
  ov.z = f2bf(((o4.z - mean) * rstd * ga4.z + be4.z + s3 * v4.z) * g4.z);
  ov.w = f2bf(((o4.w - mean) * rstd * ga4.w + be4.w + s3 * v4.w) * g4.w);
  *(ushort4*)(yg + btc) = ov;
}

// ---------------------------------------------------------------------------
extern "C" void kernel_launch(void* const* d_in, const int* in_sizes, int n_in,
                              void* d_out, int out_size, void* d_ws, size_t ws_size,
                              hipStream_t stream)
{
  (void)in_sizes; (void)n_in; (void)out_size;
  const float* x    = (const float*)d_in[0];
  const float* x_r  = (const float*)d_in[1];
  const float* x_w  = (const float*)d_in[2];
  const float* x_k  = (const float*)d_in[3];
  const float* x_v  = (const float*)d_in[4];
  const float* x_a  = (const float*)d_in[5];
  const float* x_g  = (const float*)d_in[6];
  const float* w0   = (const float*)d_in[7];
  const float* w1   = (const float*)d_in[8];
  const float* w2   = (const float*)d_in[9];
  const float* a0   = (const float*)d_in[10];
  const float* a1   = (const float*)d_in[11];
  const float* a2   = (const float*)d_in[12];
  const float* g1   = (const float*)d_in[16];
  const float* g2   = (const float*)d_in[17];
  const float* k_k  = (const float*)d_in[18];
  const float* k_a  = (const float*)d_in[19];
  const float* r_k  = (const float*)d_in[20];
  const float* Wr   = (const float*)d_in[21];
  const float* Wk   = (const float*)d_in[22];
  const float* Wv   = (const float*)d_in[23];
  const float* Wo   = (const float*)d_in[24];
  const float* ln_g = (const float*)d_in[25];
  const float* ln_b = (const float*)d_in[26];

  float* outp = (float*)d_out;
  float* vfirst = outp + (size_t)BB * TT * CCH;

  char* ws = (char*)d_ws;
  size_t off = 0;
  auto alloc = [&](size_t bytes) -> char* {
    char* p = ws + off;
    off += (bytes + 255) & ~(size_t)255;
    return p;
  };

  unsigned short* WrT = (unsigned short*)alloc(2097152);
  unsigned short* WkT = (unsigned short*)alloc(2097152);
  unsigned short* WvT = (unsigned short*)alloc(2097152);
  unsigned short* WoT = (unsigned short*)alloc(2097152);
  unsigned short* w1T = (unsigned short*)alloc(131072);
  unsigned short* w2T = (unsigned short*)alloc(131072);
  unsigned short* a1T = (unsigned short*)alloc(131072);
  unsigned short* a2T = (unsigned short*)alloc(131072);
  unsigned short* g1T = (unsigned short*)alloc(262144);
  unsigned short* g2T = (unsigned short*)alloc(262144);
  unsigned short* xrB = (unsigned short*)alloc(8388608);
  unsigned short* xwB = (unsigned short*)alloc(8388608);
  unsigned short* xkB = (unsigned short*)alloc(8388608);
  unsigned short* xvB = (unsigned short*)alloc(8388608);
  unsigned short* xaB = (unsigned short*)alloc(8388608);
  unsigned short* xgB = (unsigned short*)alloc(8388608);
  float* r_s  = (float*)alloc(16777216);
  float* k_s  = (float*)alloc(16777216);
  float* v_s  = (float*)alloc(16777216);
  float* w_s  = (float*)alloc(16777216);   // log-decay lw
  float* aa_s = (float*)alloc(16777216);
  float* bb_s = (float*)alloc(16777216);
  float* wraw = (float*)alloc(16777216);
  float* araw = (float*)alloc(16777216);
  unsigned short* hwB = (unsigned short*)alloc(524288);
  unsigned short* haB = (unsigned short*)alloc(524288);
  unsigned short* hgB = (unsigned short*)alloc(1048576);
  unsigned short* ygB = (unsigned short*)alloc(8388608);

  // aliases for the chunked-scan stage (owners dead by then)
  float* McG = (float*)xrB;   // 16.78 MB over xrB+xwB
  float* NcG = (float*)xkB;   // over xkB+xvB
  float* PcG = (float*)xaB;   // over xaB+xgB
  float* OlG = wraw;          // 16.78 MB
  float* Sch = aa_s;          // chunk-entry states
  float* o_buf = bb_s;        // scan output o
  float* g_f = araw;          // gate

  if (off > ws_size) return;

  dim3 blk(256);

  transpose_bf16_kernel<<<dim3(16, 16), blk, 0, stream>>>(Wr, WrT, 1024, 1024);
  transpose_bf16_kernel<<<dim3(16, 16), blk, 0, stream>>>(Wk, WkT, 1024, 1024);
  transpose_bf16_kernel<<<dim3(16, 16), blk, 0, stream>>>(Wv, WvT, 1024, 1024);
  transpose_bf16_kernel<<<dim3(16, 16), blk, 0, stream>>>(Wo, WoT, 1024, 1024);
  transpose_bf16_kernel<<<dim3(16, 1), blk, 0, stream>>>(w1, w1T, 1024, 64);
  transpose_bf16_kernel<<<dim3(1, 16), blk, 0, stream>>>(w2, w2T, 64, 1024);
  transpose_bf16_kernel<<<dim3(16, 1), blk, 0, stream>>>(a1, a1T, 1024, 64);
  transpose_bf16_kernel<<<dim3(1, 16), blk, 0, stream>>>(a2, a2T, 64, 1024);
  transpose_bf16_kernel<<<dim3(16, 2), blk, 0, stream>>>(g1, g1T, 1024, 128);
  transpose_bf16_kernel<<<dim3(2, 16), blk, 0, stream>>>(g2, g2T, 128, 1024);

  mix_kernel<<<4096, blk, 0, stream>>>(x, x_r, x_w, x_k, x_v, x_a, x_g,
                                       xrB, xwB, xkB, xvB, xaB, xgB);

  gemm_bt_kernel<128, 4><<<dim3(32, 8), blk, 0, stream>>>(xrB, WrT, r_s, nullptr, nullptr, 4096, 1024, 1024);
  gemm_bt_kernel<128, 4><<<dim3(32, 8), blk, 0, stream>>>(xkB, WkT, k_s, nullptr, nullptr, 4096, 1024, 1024);
  gemm_bt_kernel<128, 5><<<dim3(32, 8), blk, 0, stream>>>(xvB, WvT, v_s, nullptr, vfirst, 4096, 1024, 1024);

  gemm_bt_kernel<64, 2><<<dim3(32, 1), blk, 0, stream>>>(xwB, w1T, nullptr, hwB, nullptr, 4096, 64, 1024);
  gemm_bt_kernel<128, 0><<<dim3(32, 8), blk, 0, stream>>>(hwB, w2T, wraw, nullptr, nullptr, 4096, 1024, 64);

  gemm_bt_kernel<64, 1><<<dim3(32, 1), blk, 0, stream>>>(xaB, a1T, nullptr, haB, nullptr, 4096, 64, 1024);
  gemm_bt_kernel<128, 0><<<dim3(32, 8), blk, 0, stream>>>(haB, a2T, araw, nullptr, nullptr, 4096, 1024, 64);

  postproc_kernel<<<4096, blk, 0, stream>>>(k_s, w_s, aa_s, bb_s, wraw, araw, w0, a0, k_k, k_a);

  // g path (consumes xgB BEFORE PcG overlays it)
  gemm_bt_kernel<128, 3><<<dim3(32, 1), blk, 0, stream>>>(xgB, g1T, nullptr, hgB, nullptr, 4096, 128, 1024);
  gemm_bt_kernel<128, 0><<<dim3(32, 8), blk, 0, stream>>>(hgB, g2T, g_f, nullptr, nullptr, 4096, 1024, 128);

  // chunked-DPLR scan
  hipFuncSetAttribute((const void*)chunk_ops_kernel,
                      hipFuncAttributeMaxDynamicSharedMemorySize, 151040);
  chunk_ops_kernel<<<1024, blk, 151040, stream>>>(r_s, w_s, k_s, v_s, aa_s, bb_s,
                                                  McG, NcG, PcG, OlG);
  chunk_scan_kernel<<<64, blk, 0, stream>>>(McG, NcG, Sch);
  chunk_out_kernel<<<1024, blk, 0, stream>>>(PcG, OlG, Sch, o_buf);

  gn_kernel<<<4096, blk, 0, stream>>>(o_buf, r_s, k_s, vfirst, g_f, ln_g, ln_b, r_k, ygB);

  gemm_bt_kernel<128, 0><<<dim3(32, 8), blk, 0, stream>>>(ygB, WoT, outp, nullptr, nullptr, 4096, 1024, 1024);
}

// Round 4
// 565.950 us; speedup vs baseline: 3.2411x; 1.2419x over previous
//
#include <hip/hip_runtime.h>
#include <hip/hip_bf16.h>
#include <math.h>

// Problem constants
#define BB 4
#define TT 1024
#define CCH 1024
#define HH 16
#define NNd 64
#define LCH 64      // chunk length
#define NCHK 16     // chunks per sequence
#define PAD 65      // fp32 LDS row pad (chunk_scan/out)
#define RS 72       // bf16 LDS row stride in shorts (144B, 16B-aligned frags)
#define FS 68       // fp32 LDS row stride in floats (chunk_ops)

typedef short bf16x8 __attribute__((ext_vector_type(8)));
typedef float f32x4 __attribute__((ext_vector_type(4)));

__device__ __forceinline__ unsigned short f2bf(float f) {
  __hip_bfloat16 h = __float2bfloat16(f);
  return __builtin_bit_cast(unsigned short, h);
}
__device__ __forceinline__ float bf2f(unsigned short u) {
  unsigned int x = (unsigned int)u << 16;
  return __builtin_bit_cast(float, x);
}
__device__ __forceinline__ float sigmoidf_(float x) { return 1.0f / (1.0f + expf(-x)); }

// ---------------------------------------------------------------------------
// Transpose tile helper + 2 consolidated transpose kernels
// ---------------------------------------------------------------------------
__device__ __forceinline__ void transpose_tile(
    const float* __restrict__ in, unsigned short* __restrict__ out,
    int R, int Cc, int r0, int c0, unsigned short (*tile)[68], int t)
{
  const int rr = t >> 4;
  const int cc = (t & 15) * 4;
#pragma unroll
  for (int p = 0; p < 4; ++p) {
    int row = p * 16 + rr;
    float4 v = *(const float4*)(in + (size_t)(r0 + row) * Cc + c0 + cc);
    tile[row][cc]     = f2bf(v.x);
    tile[row][cc + 1] = f2bf(v.y);
    tile[row][cc + 2] = f2bf(v.z);
    tile[row][cc + 3] = f2bf(v.w);
  }
  __syncthreads();
#pragma unroll
  for (int p = 0; p < 4; ++p) {
    int row = p * 16 + rr;
    ushort4 o;
    o.x = tile[cc][row];
    o.y = tile[cc + 1][row];
    o.z = tile[cc + 2][row];
    o.w = tile[cc + 3][row];
    *(ushort4*)(out + (size_t)(c0 + row) * R + r0 + cc) = o;
  }
}

__global__ __launch_bounds__(256) void transpose_big4_kernel(
    const float* __restrict__ W0, const float* __restrict__ W1,
    const float* __restrict__ W2, const float* __restrict__ W3,
    unsigned short* __restrict__ T0, unsigned short* __restrict__ T1,
    unsigned short* __restrict__ T2, unsigned short* __restrict__ T3)
{
  __shared__ unsigned short tile[64][68];
  const float* src = (blockIdx.z == 0) ? W0 : (blockIdx.z == 1) ? W1 : (blockIdx.z == 2) ? W2 : W3;
  unsigned short* dst = (blockIdx.z == 0) ? T0 : (blockIdx.z == 1) ? T1 : (blockIdx.z == 2) ? T2 : T3;
  transpose_tile(src, dst, 1024, 1024, blockIdx.x * 64, blockIdx.y * 64, tile, threadIdx.x);
}

__global__ __launch_bounds__(256) void transpose_lora_kernel(
    const float* __restrict__ w1, const float* __restrict__ w2,
    const float* __restrict__ a1, const float* __restrict__ a2,
    const float* __restrict__ g1, const float* __restrict__ g2,
    unsigned short* __restrict__ w1T, unsigned short* __restrict__ w2T,
    unsigned short* __restrict__ a1T, unsigned short* __restrict__ a2T,
    unsigned short* __restrict__ g1T, unsigned short* __restrict__ g2T)
{
  __shared__ unsigned short tile[64][68];
  const int i = blockIdx.x;
  const float* src; unsigned short* dst; int R, C, rt, ct;
  if (i < 16)      { src = w1; dst = w1T; R = 1024; C = 64;   rt = i;      ct = 0; }
  else if (i < 32) { src = w2; dst = w2T; R = 64;   C = 1024; rt = 0;      ct = i - 16; }
  else if (i < 48) { src = a1; dst = a1T; R = 1024; C = 64;   rt = i - 32; ct = 0; }
  else if (i < 64) { src = a2; dst = a2T; R = 64;   C = 1024; rt = 0;      ct = i - 48; }
  else if (i < 96) { int k = i - 64; src = g1; dst = g1T; R = 1024; C = 128; rt = k >> 1; ct = k & 1; }
  else             { int k = i - 96; src = g2; dst = g2T; R = 128; C = 1024; rt = k & 1;  ct = k >> 1; }
  transpose_tile(src, dst, R, C, rt * 64, ct * 64, tile, threadIdx.x);
}

// ---------------------------------------------------------------------------
// Token-shift mix
// ---------------------------------------------------------------------------
__global__ __launch_bounds__(256) void mix_kernel(
    const float* __restrict__ x,
    const float* __restrict__ cr, const float* __restrict__ cw,
    const float* __restrict__ ck, const float* __restrict__ cv,
    const float* __restrict__ ca, const float* __restrict__ cg,
    unsigned short* __restrict__ xr, unsigned short* __restrict__ xw,
    unsigned short* __restrict__ xk, unsigned short* __restrict__ xv,
    unsigned short* __restrict__ xa, unsigned short* __restrict__ xg)
{
  const size_t idx = ((size_t)blockIdx.x * 256 + threadIdx.x) * 4;
  const int c = (int)(idx & 1023);
  const int t = (int)((idx >> 10) & 1023);
  float4 xc = *(const float4*)(x + idx);
  float4 xp = make_float4(0.f, 0.f, 0.f, 0.f);
  if (t > 0) xp = *(const float4*)(x + idx - 1024);
  float4 dx = make_float4(xp.x - xc.x, xp.y - xc.y, xp.z - xc.z, xp.w - xc.w);
  auto st = [&](unsigned short* dst, const float* coef) {
    float4 w = *(const float4*)(coef + c);
    ushort4 o;
    o.x = f2bf(fmaf(dx.x, w.x, xc.x));
    o.y = f2bf(fmaf(dx.y, w.y, xc.y));
    o.z = f2bf(fmaf(dx.z, w.z, xc.z));
    o.w = f2bf(fmaf(dx.w, w.w, xc.w));
    *(ushort4*)(dst + idx) = o;
  };
  st(xr, cr); st(xw, cw); st(xk, ck); st(xv, cv); st(xa, ca); st(xg, cg);
}

// ---------------------------------------------------------------------------
// bf16 MFMA GEMM, B transposed (BT = [N][K]).
// EPI: 0=f32 rowmajor, 1=bf16 rowmajor, 2=bf16 tanh, 3=bf16 sigmoid,
//      4=f32 scan layout [B,H,T,N], 5=scan + f32 rowmajor dual (for v)
// ---------------------------------------------------------------------------
template<int BN, int EPI>
__global__ __launch_bounds__(256) void gemm_bt_kernel(
    const unsigned short* __restrict__ A,
    const unsigned short* __restrict__ BT,
    float* __restrict__ out,
    unsigned short* __restrict__ outb,
    float* __restrict__ out2,
    int M, int N, int K)
{
  constexpr int BM = 128, BK = 32, SK = 40;
  __shared__ __align__(16) unsigned short As[BM * SK];
  __shared__ __align__(16) unsigned short Bs[BN * SK];
  const int tid = threadIdx.x;
  const int wv = tid >> 6, lane = tid & 63;
  const int fr = lane & 15, q = lane >> 4;
  constexpr int WMS = (BN == 128) ? 2 : 4;
  constexpr int TM = BM / WMS / 16;
  constexpr int TN = 4;
  const int wave_m = (BN == 128) ? (wv >> 1) : wv;
  const int wave_n = (BN == 128) ? (wv & 1) : 0;
  const int m0 = blockIdx.x * BM;
  const int n0 = blockIdx.y * BN;

  f32x4 acc[TM][TN];
#pragma unroll
  for (int i = 0; i < TM; i++)
#pragma unroll
    for (int j = 0; j < TN; j++) acc[i][j] = (f32x4){0.f, 0.f, 0.f, 0.f};

  const int arow = tid >> 2;
  const int akc = (tid & 3) * 8;

  for (int k0 = 0; k0 < K; k0 += BK) {
#pragma unroll
    for (int i = 0; i < 2; ++i) {
      int row = arow + i * 64;
      uint4 v = *(const uint4*)(A + (size_t)(m0 + row) * K + k0 + akc);
      *(uint4*)(&As[row * SK + akc]) = v;
    }
#pragma unroll
    for (int i = 0; i < BN / 64; ++i) {
      int row = arow + i * 64;
      uint4 v = *(const uint4*)(BT + (size_t)(n0 + row) * K + k0 + akc);
      *(uint4*)(&Bs[row * SK + akc]) = v;
    }
    __syncthreads();
    bf16x8 af[TM], bfv[TN];
#pragma unroll
    for (int i = 0; i < TM; i++)
      af[i] = *(const bf16x8*)(&As[(wave_m * TM * 16 + i * 16 + fr) * SK + q * 8]);
#pragma unroll
    for (int j = 0; j < TN; j++)
      bfv[j] = *(const bf16x8*)(&Bs[(wave_n * 64 + j * 16 + fr) * SK + q * 8]);
#pragma unroll
    for (int i = 0; i < TM; i++)
#pragma unroll
      for (int j = 0; j < TN; j++)
        acc[i][j] = __builtin_amdgcn_mfma_f32_16x16x32_bf16(af[i], bfv[j], acc[i][j], 0, 0, 0);
    __syncthreads();
  }

#pragma unroll
  for (int i = 0; i < TM; i++) {
#pragma unroll
    for (int j = 0; j < TN; j++) {
      const int mb = m0 + wave_m * TM * 16 + i * 16 + q * 4;
      const int n = n0 + wave_n * 64 + j * 16 + fr;
#pragma unroll
      for (int r = 0; r < 4; r++) {
        const int m = mb + r;
        float val = acc[i][j][r];
        if constexpr (EPI == 0) {
          out[(size_t)m * N + n] = val;
        } else if constexpr (EPI == 1) {
          outb[(size_t)m * N + n] = f2bf(val);
        } else if constexpr (EPI == 2) {
          outb[(size_t)m * N + n] = f2bf(tanhf(val));
        } else if constexpr (EPI == 3) {
          outb[(size_t)m * N + n] = f2bf(sigmoidf_(val));
        } else {
          const int b = m >> 10, t = m & 1023, h = n >> 6, nn = n & 63;
          const size_t sidx = ((size_t)((b << 4) + h) << 16) + ((size_t)t << 6) + nn;
          out[sidx] = val;
          if constexpr (EPI == 5) out2[(size_t)m * N + n] = val;
        }
      }
    }
  }
}

// ---------------------------------------------------------------------------
// Postproc: a = sigmoid(a0+araw); kk = normalize(k*k_k); aa=-kk, bb=kk*a;
// kmod in-place; lw = log decay = -e^{-1/2} * sigmoid(w0+wraw)
// ---------------------------------------------------------------------------
__global__ __launch_bounds__(256) void postproc_kernel(
    float* __restrict__ k_s, float* __restrict__ lw_s,
    float* __restrict__ aa_s, float* __restrict__ bb_s,
    const float* __restrict__ wraw, const float* __restrict__ araw,
    const float* __restrict__ w0, const float* __restrict__ a0,
    const float* __restrict__ k_k, const float* __restrict__ k_a)
{
  const int bt = blockIdx.x;
  const int b = bt >> 10, t = bt & 1023;
  const int tid = threadIdx.x;
  const int c = tid * 4;
  const int h = tid >> 4;
  const int n = c & 63;
  const size_t btc = (size_t)bt * CCH + c;
  const size_t sidx = ((size_t)((b << 4) + h) << 16) + ((size_t)t << 6) + n;

  float4 k4 = *(const float4*)(k_s + sidx);
  float4 wr4 = *(const float4*)(wraw + btc);
  float4 ar4 = *(const float4*)(araw + btc);
  float4 w04 = *(const float4*)(w0 + c);
  float4 a04 = *(const float4*)(a0 + c);
  float4 kkc = *(const float4*)(k_k + c);
  float4 ka4 = *(const float4*)(k_a + c);

  float4 a4;
  a4.x = sigmoidf_(a04.x + ar4.x);
  a4.y = sigmoidf_(a04.y + ar4.y);
  a4.z = sigmoidf_(a04.z + ar4.z);
  a4.w = sigmoidf_(a04.w + ar4.w);

  float4 kk;
  kk.x = k4.x * kkc.x; kk.y = k4.y * kkc.y; kk.z = k4.z * kkc.z; kk.w = k4.w * kkc.w;
  float ss = kk.x * kk.x + kk.y * kk.y + kk.z * kk.z + kk.w * kk.w;
  ss += __shfl_xor(ss, 1);
  ss += __shfl_xor(ss, 2);
  ss += __shfl_xor(ss, 4);
  ss += __shfl_xor(ss, 8);
  const float scale = 1.0f / fmaxf(sqrtf(ss), 1e-12f);

  float4 aa4, bb4;
  aa4.x = -kk.x * scale; bb4.x = kk.x * scale * a4.x;
  aa4.y = -kk.y * scale; bb4.y = kk.y * scale * a4.y;
  aa4.z = -kk.z * scale; bb4.z = kk.z * scale * a4.z;
  aa4.w = -kk.w * scale; bb4.w = kk.w * scale * a4.w;

  float4 km;
  km.x = k4.x * (1.0f + (a4.x - 1.0f) * ka4.x);
  km.y = k4.y * (1.0f + (a4.y - 1.0f) * ka4.y);
  km.z = k4.z * (1.0f + (a4.z - 1.0f) * ka4.z);
  km.w = k4.w * (1.0f + (a4.w - 1.0f) * ka4.w);

  const float EM = 0.60653065971263342f;  // e^{-0.5}
  float4 lw;
  lw.x = -EM * sigmoidf_(w04.x + wr4.x);
  lw.y = -EM * sigmoidf_(w04.y + wr4.y);
  lw.z = -EM * sigmoidf_(w04.z + wr4.z);
  lw.w = -EM * sigmoidf_(w04.w + wr4.w);

  *(float4*)(k_s + sidx) = km;
  *(float4*)(lw_s + sidx) = lw;
  *(float4*)(aa_s + sidx) = aa4;
  *(float4*)(bb_s + sidx) = bb4;
}

// ---------------------------------------------------------------------------
// Phase 1 (MFMA): per-(bh,chunk) chunked-DPLR operators.
// ST' = Mc ST + Ncc,  Out = Pc ST + Oloc   (ST = S^T, key x value)
// Mc = diag(e^{gL}) + Btil^T X ; Ncc = Btil^T Qloc + Ktil^T V
// Pc = Rhat + DBR X            ; Oloc = DBR Qloc + DKR V
// g=cumsum(lw); Ahat=a*e^{g[t-1]}; Bp=b*e^{-g}; Kp=k*e^{-g}; Rhat=r*e^{g};
// Btil=Bp*e^{gL}(col); LBA=strictlow(Ahat Bp^T); LKA=strictlow(Ahat Kp^T);
// DBR=low(Rhat Bp^T); DKR=low(Rhat Kp^T);
// [X|Y] = (I-LBA)^{-1}[Ahat|LKA]; Qloc = Y V.
// All 64^3 products on MFMA (bf16 in, fp32 accum); trisolve scalar fp32.
// ---------------------------------------------------------------------------
__global__ __launch_bounds__(256, 1) void chunk_ops_kernel(
    const float* __restrict__ r_s, const float* __restrict__ lw_s,
    const float* __restrict__ k_s, const float* __restrict__ v_s,
    const float* __restrict__ aa_s, const float* __restrict__ bb_s,
    float* __restrict__ McG, float* __restrict__ NcG,
    float* __restrict__ PcG, float* __restrict__ OlG)
{
  extern __shared__ char smraw[];
  unsigned short* AHb  = (unsigned short*)smraw;   // Ahat [t][j]
  unsigned short* RHb  = AHb  + 64 * RS;           // Rhat [t][j]
  unsigned short* BPb  = RHb  + 64 * RS;           // Bp   [s][j]
  unsigned short* KPb  = BPb  + 64 * RS;           // Kp   [s][j]
  unsigned short* BPTb = KPb  + 64 * RS;           // Btil^T [i][t]
  unsigned short* KPTb = BPTb + 64 * RS;           // Ktil^T [i][t]
  unsigned short* VSTb = KPTb + 64 * RS;           // V^T  [n][t]
  unsigned short* XTb  = VSTb + 64 * RS;           // X^T  [j][t]
  unsigned short* LKb  = XTb  + 64 * RS;           // LKA -> Y [t][s]
  unsigned short* QTb  = LKb  + 64 * RS;           // Qloc^T [n][t]
  unsigned short* DBb  = QTb  + 64 * RS;           // DBR  [t][s]
  unsigned short* DKb  = DBb  + 64 * RS;           // DKR  [t][s]
  float* LBf = (float*)(DKb + 64 * RS);            // LBA fp32 [t][s]
  float* RHf = LBf + 64 * FS;                      // Rhat fp32 [t][j]
  float* GLe = RHf + 64 * FS;                      // e^{gL} [64]
  float* SS  = GLe + 64;                           // [4][64] strip sums

  const int inst = blockIdx.x;
  const int bh = inst >> 4, c = inst & 15;
  const size_t cb = ((size_t)bh << 16) + ((size_t)c << 12);
  const int tid = threadIdx.x;
  const int lane = tid & 63;
  const int wv = tid >> 6;
  const int jl = lane;

  // ---- log-decay cumsum ----
  float g[16];
  {
    float run = 0.f;
#pragma unroll
    for (int u = 0; u < 16; ++u) {
      run += lw_s[cb + (size_t)(16 * wv + u) * 64 + jl];
      g[u] = run;
    }
    SS[wv * 64 + jl] = run;
  }
  __syncthreads();
  const float ss0 = SS[0 * 64 + jl], ss1 = SS[1 * 64 + jl];
  const float ss2 = SS[2 * 64 + jl], ss3 = SS[3 * 64 + jl];
  const float goff = (wv > 0 ? ss0 : 0.f) + (wv > 1 ? ss1 : 0.f) + (wv > 2 ? ss2 : 0.f);
  const float gl = ss0 + ss1 + ss2 + ss3;
#pragma unroll
  for (int u = 0; u < 16; ++u) g[u] += goff;
  if (wv == 0) GLe[jl] = expf(gl);

  // ---- build transformed factor matrices (bf16) ----
#pragma unroll
  for (int u = 0; u < 16; ++u) {
    const int t = 16 * wv + u;
    const size_t gi = cb + (size_t)t * 64 + jl;
    const float gm1 = (u == 0) ? goff : g[u - 1];
    const float av = aa_s[gi], bv = bb_s[gi], kv = k_s[gi], rv = r_s[gi], vv = v_s[gi];
    AHb[t * RS + jl] = f2bf(av * expf(gm1));
    const float em = expf(-g[u]);
    BPb[t * RS + jl] = f2bf(bv * em);
    KPb[t * RS + jl] = f2bf(kv * em);
    const float egl = expf(gl - g[u]);     // <= 1
    BPTb[jl * RS + t] = f2bf(bv * egl);
    KPTb[jl * RS + t] = f2bf(kv * egl);
    const float rh = rv * expf(g[u]);
    RHb[t * RS + jl] = f2bf(rh);
    RHf[t * FS + jl] = rh;
    VSTb[jl * RS + t] = f2bf(vv);
  }
  __syncthreads();

  const int fr = lane & 15, q = lane >> 4;
  const int i0 = wv * 16;

  // ---- Gram products via MFMA: LBA, LKA, DBR, DKR ----
  {
    f32x4 aLB[4], aLK[4], aDB[4], aDK[4];
#pragma unroll
    for (int j = 0; j < 4; ++j) {
      aLB[j] = (f32x4){0.f, 0.f, 0.f, 0.f}; aLK[j] = (f32x4){0.f, 0.f, 0.f, 0.f};
      aDB[j] = (f32x4){0.f, 0.f, 0.f, 0.f}; aDK[j] = (f32x4){0.f, 0.f, 0.f, 0.f};
    }
#pragma unroll
    for (int ks = 0; ks < 2; ++ks) {
      const int ko = ks * 32 + q * 8;
      bf16x8 fA = *(const bf16x8*)(AHb + (i0 + fr) * RS + ko);
      bf16x8 fR = *(const bf16x8*)(RHb + (i0 + fr) * RS + ko);
#pragma unroll
      for (int j = 0; j < 4; ++j) {
        bf16x8 fB = *(const bf16x8*)(BPb + (j * 16 + fr) * RS + ko);
        bf16x8 fK = *(const bf16x8*)(KPb + (j * 16 + fr) * RS + ko);
        aLB[j] = __builtin_amdgcn_mfma_f32_16x16x32_bf16(fA, fB, aLB[j], 0, 0, 0);
        aLK[j] = __builtin_amdgcn_mfma_f32_16x16x32_bf16(fA, fK, aLK[j], 0, 0, 0);
        aDB[j] = __builtin_amdgcn_mfma_f32_16x16x32_bf16(fR, fB, aDB[j], 0, 0, 0);
        aDK[j] = __builtin_amdgcn_mfma_f32_16x16x32_bf16(fR, fK, aDK[j], 0, 0, 0);
      }
    }
    // C layout: row = i0 + q*4 + r, col = j*16 + fr ; mask & store
#pragma unroll
    for (int j = 0; j < 4; ++j) {
      const int s = j * 16 + fr;
#pragma unroll
      for (int r = 0; r < 4; ++r) {
        const int t = i0 + q * 4 + r;
        LBf[t * FS + s] = (s < t) ? aLB[j][r] : 0.f;
        LKb[t * RS + s] = f2bf((s < t) ? aLK[j][r] : 0.f);
        DBb[t * RS + s] = f2bf((s <= t) ? aDB[j][r] : 0.f);
        DKb[t * RS + s] = f2bf((s <= t) ? aDK[j][r] : 0.f);
      }
    }
  }
  __syncthreads();

  // ---- triangular solve (I-LBA)[X|Y] = [Ahat|LKA] (fp32, 128 threads) ----
  if (tid < 128) {
    const int jc = lane;
    const bool isX = (wv == 0);
    float x[64];
#pragma unroll
    for (int t = 0; t < 64; ++t)
      x[t] = bf2f(isX ? AHb[t * RS + jc] : LKb[t * RS + jc]);
#pragma unroll
    for (int t = 1; t < 64; ++t) {
      float a0 = 0.f, a1 = 0.f, a2 = 0.f, a3 = 0.f;
      const float* lr = LBf + t * FS;
#pragma unroll
      for (int s = 0; s + 4 <= t; s += 4) {
        float4 l4 = *(const float4*)(lr + s);
        a0 = fmaf(l4.x, x[s], a0);     a1 = fmaf(l4.y, x[s + 1], a1);
        a2 = fmaf(l4.z, x[s + 2], a2); a3 = fmaf(l4.w, x[s + 3], a3);
      }
#pragma unroll
      for (int s = t & ~3; s < t; ++s) a0 = fmaf(lr[s], x[s], a0);
      x[t] += (a0 + a1) + (a2 + a3);
    }
    if (isX) {
#pragma unroll
      for (int t = 0; t < 64; t += 2) {
        unsigned int pk = (unsigned int)f2bf(x[t]) | ((unsigned int)f2bf(x[t + 1]) << 16);
        *(unsigned int*)(XTb + jc * RS + t) = pk;
      }
    } else {
#pragma unroll
      for (int t = 0; t < 64; ++t) LKb[t * RS + jc] = f2bf(x[t]);
    }
  }
  __syncthreads();

  // ---- Qloc = Y V (MFMA) -> QT[n][t] ----
  {
    f32x4 qa[4];
#pragma unroll
    for (int j = 0; j < 4; ++j) qa[j] = (f32x4){0.f, 0.f, 0.f, 0.f};
#pragma unroll
    for (int ks = 0; ks < 2; ++ks) {
      const int ko = ks * 32 + q * 8;
      bf16x8 fY = *(const bf16x8*)(LKb + (i0 + fr) * RS + ko);
#pragma unroll
      for (int j = 0; j < 4; ++j) {
        bf16x8 fV = *(const bf16x8*)(VSTb + (j * 16 + fr) * RS + ko);
        qa[j] = __builtin_amdgcn_mfma_f32_16x16x32_bf16(fY, fV, qa[j], 0, 0, 0);
      }
    }
#pragma unroll
    for (int j = 0; j < 4; ++j) {
      const int n = j * 16 + fr;
      ushort4 pk;
      pk.x = f2bf(qa[j][0]); pk.y = f2bf(qa[j][1]);
      pk.z = f2bf(qa[j][2]); pk.w = f2bf(qa[j][3]);
      *(ushort4*)(QTb + n * RS + i0 + q * 4) = pk;
    }
  }
  __syncthreads();

  // ---- final operators: Mc, Ncc, Pc, Oloc (MFMA) -> global ----
  {
    f32x4 mA[4], nA[4], pA[4], oA[4];
#pragma unroll
    for (int j = 0; j < 4; ++j) {
      mA[j] = (f32x4){0.f, 0.f, 0.f, 0.f}; nA[j] = (f32x4){0.f, 0.f, 0.f, 0.f};
      pA[j] = (f32x4){0.f, 0.f, 0.f, 0.f}; oA[j] = (f32x4){0.f, 0.f, 0.f, 0.f};
    }
#pragma unroll
    for (int ks = 0; ks < 2; ++ks) {
      const int ko = ks * 32 + q * 8;
      bf16x8 fBT = *(const bf16x8*)(BPTb + (i0 + fr) * RS + ko);
      bf16x8 fKT = *(const bf16x8*)(KPTb + (i0 + fr) * RS + ko);
      bf16x8 fDB = *(const bf16x8*)(DBb + (i0 + fr) * RS + ko);
      bf16x8 fDK = *(const bf16x8*)(DKb + (i0 + fr) * RS + ko);
#pragma unroll
      for (int j = 0; j < 4; ++j) {
        bf16x8 fXT = *(const bf16x8*)(XTb + (j * 16 + fr) * RS + ko);
        bf16x8 fQT = *(const bf16x8*)(QTb + (j * 16 + fr) * RS + ko);
        bf16x8 fVT = *(const bf16x8*)(VSTb + (j * 16 + fr) * RS + ko);
        mA[j] = __builtin_amdgcn_mfma_f32_16x16x32_bf16(fBT, fXT, mA[j], 0, 0, 0);
        nA[j] = __builtin_amdgcn_mfma_f32_16x16x32_bf16(fBT, fQT, nA[j], 0, 0, 0);
        nA[j] = __builtin_amdgcn_mfma_f32_16x16x32_bf16(fKT, fVT, nA[j], 0, 0, 0);
        pA[j] = __builtin_amdgcn_mfma_f32_16x16x32_bf16(fDB, fXT, pA[j], 0, 0, 0);
        oA[j] = __builtin_amdgcn_mfma_f32_16x16x32_bf16(fDB, fQT, oA[j], 0, 0, 0);
        oA[j] = __builtin_amdgcn_mfma_f32_16x16x32_bf16(fDK, fVT, oA[j], 0, 0, 0);
      }
    }
    const size_t ob = (size_t)inst * 4096;
#pragma unroll
    for (int j = 0; j < 4; ++j) {
      const int col = j * 16 + fr;
#pragma unroll
      for (int r = 0; r < 4; ++r) {
        const int row = i0 + q * 4 + r;
        const size_t oi = ob + (size_t)row * 64 + col;
        McG[oi] = mA[j][r] + (row == col ? GLe[row] : 0.f);
        NcG[oi] = nA[j][r];
        PcG[oi] = pA[j][r] + RHf[row * FS + col];
        OlG[oi] = oA[j][r];
      }
    }
  }
}

// ---------------------------------------------------------------------------
// Phase 2: sequential chunk-state propagation per (b,h): ST' = Mc ST + Ncc.
// ---------------------------------------------------------------------------
__global__ __launch_bounds__(256) void chunk_scan_kernel(
    const float* __restrict__ McG, const float* __restrict__ NcG,
    float* __restrict__ Sch)
{
  __shared__ float ST[64 * PAD];
  __shared__ float MB[64 * PAD];
  const int bh = blockIdx.x;
  const int tid = threadIdx.x;
  const int it = tid >> 4, jt = tid & 15;

#pragma unroll
  for (int q = 0; q < 16; ++q) {
    int idx = q * 256 + tid;
    ST[(idx >> 6) * PAD + (idx & 63)] = 0.f;
  }
  __syncthreads();

  for (int c = 0; c < 16; ++c) {
    const size_t ob = ((((size_t)bh << 4) + c) << 12);
#pragma unroll
    for (int q = 0; q < 4; ++q) {
      int idx = q * 1024 + tid * 4;
      int row = idx >> 6, col = idx & 63;
      float4 sv = make_float4(ST[row * PAD + col], ST[row * PAD + col + 1],
                              ST[row * PAD + col + 2], ST[row * PAD + col + 3]);
      *(float4*)(Sch + ob + idx) = sv;
      float4 mv = *(const float4*)(McG + ob + idx);
      MB[row * PAD + col] = mv.x; MB[row * PAD + col + 1] = mv.y;
      MB[row * PAD + col + 2] = mv.z; MB[row * PAD + col + 3] = mv.w;
    }
    __syncthreads();
    float acc[4][4];
#pragma unroll
    for (int u = 0; u < 4; ++u) {
      float4 n4 = *(const float4*)(NcG + ob + (size_t)(4 * it + u) * 64 + 4 * jt);
      acc[u][0] = n4.x; acc[u][1] = n4.y; acc[u][2] = n4.z; acc[u][3] = n4.w;
    }
#pragma unroll 4
    for (int pp = 0; pp < 64; ++pp) {
      float mv[4], sv[4];
#pragma unroll
      for (int u = 0; u < 4; ++u) mv[u] = MB[(4 * it + u) * PAD + pp];
#pragma unroll
      for (int v = 0; v < 4; ++v) sv[v] = ST[pp * PAD + 4 * jt + v];
#pragma unroll
      for (int u = 0; u < 4; ++u)
#pragma unroll
        for (int v = 0; v < 4; ++v) acc[u][v] = fmaf(mv[u], sv[v], acc[u][v]);
    }
    __syncthreads();
#pragma unroll
    for (int u = 0; u < 4; ++u)
#pragma unroll
      for (int v = 0; v < 4; ++v) ST[(4 * it + u) * PAD + 4 * jt + v] = acc[u][v];
    __syncthreads();
  }
}

// ---------------------------------------------------------------------------
// Phase 3: Out = Pc ST + Oloc -> o[b][t][h*64+j]
// ---------------------------------------------------------------------------
__global__ __launch_bounds__(256) void chunk_out_kernel(
    const float* __restrict__ PcG, const float* __restrict__ OlG,
    const float* __restrict__ Sch, float* __restrict__ o)
{
  __shared__ float ST[64 * PAD];
  __shared__ float PB[64 * PAD];
  const int inst = blockIdx.x;
  const int bh = inst >> 4, c = inst & 15;
  const int b = bh >> 4, h = bh & 15;
  const int tid = threadIdx.x;
  const int tt = tid >> 4, jt = tid & 15;
  const size_t ob = (size_t)inst << 12;

#pragma unroll
  for (int q = 0; q < 4; ++q) {
    int idx = q * 1024 + tid * 4;
    int row = idx >> 6, col = idx & 63;
    float4 sv = *(const float4*)(Sch + ob + idx);
    ST[row * PAD + col] = sv.x; ST[row * PAD + col + 1] = sv.y;
    ST[row * PAD + col + 2] = sv.z; ST[row * PAD + col + 3] = sv.w;
    float4 pv = *(const float4*)(PcG + ob + idx);
    PB[row * PAD + col] = pv.x; PB[row * PAD + col + 1] = pv.y;
    PB[row * PAD + col + 2] = pv.z; PB[row * PAD + col + 3] = pv.w;
  }
  __syncthreads();

  float acc[4][4];
#pragma unroll
  for (int u = 0; u < 4; ++u) {
    float4 o4 = *(const float4*)(OlG + ob + (size_t)(4 * tt + u) * 64 + 4 * jt);
    acc[u][0] = o4.x; acc[u][1] = o4.y; acc[u][2] = o4.z; acc[u][3] = o4.w;
  }
#pragma unroll 4
  for (int pp = 0; pp < 64; ++pp) {
    float pv[4], sv[4];
#pragma unroll
    for (int u = 0; u < 4; ++u) pv[u] = PB[(4 * tt + u) * PAD + pp];
#pragma unroll
    for (int v = 0; v < 4; ++v) sv[v] = ST[pp * PAD + 4 * jt + v];
#pragma unroll
    for (int u = 0; u < 4; ++u)
#pragma unroll
      for (int v = 0; v < 4; ++v) acc[u][v] = fmaf(pv[u], sv[v], acc[u][v]);
  }
#pragma unroll
  for (int u = 0; u < 4; ++u) {
    const int tg = c * 64 + 4 * tt + u;
    float4 o4 = make_float4(acc[u][0], acc[u][1], acc[u][2], acc[u][3]);
    *(float4*)(o + ((size_t)b * 1024 + tg) * 1024 + h * 64 + 4 * jt) = o4;
  }
}

// ---------------------------------------------------------------------------
// GroupNorm + rwkv bonus + *g -> bf16
// ---------------------------------------------------------------------------
__global__ __launch_bounds__(256) void gn_kernel(
    const float* __restrict__ o, const float* __restrict__ r_s,
    const float* __restrict__ k_s, const float* __restrict__ v_btc,
    const float* __restrict__ g_f, const float* __restrict__ gamma,
    const float* __restrict__ beta, const float* __restrict__ r_k,
    unsigned short* __restrict__ yg)
{
  const int bt = blockIdx.x;
  const int b = bt >> 10, t = bt & 1023;
  const int tid = threadIdx.x;
  const int c = tid * 4;
  const int h = tid >> 4;
  const int n = c & 63;
  const size_t btc = (size_t)bt * CCH + c;
  const size_t sidx = ((size_t)((b << 4) + h) << 16) + ((size_t)t << 6) + n;

  float4 o4 = *(const float4*)(o + btc);
  float4 r4 = *(const float4*)(r_s + sidx);
  float4 k4 = *(const float4*)(k_s + sidx);
  float4 v4 = *(const float4*)(v_btc + btc);
  float4 rk4 = *(const float4*)(r_k + h * 64 + n);

  float s1 = o4.x + o4.y + o4.z + o4.w;
  float s2 = o4.x * o4.x + o4.y * o4.y + o4.z * o4.z + o4.w * o4.w;
  float s3 = r4.x * k4.x * rk4.x + r4.y * k4.y * rk4.y + r4.z * k4.z * rk4.z + r4.w * k4.w * rk4.w;
#pragma unroll
  for (int m = 1; m < 16; m <<= 1) {
    s1 += __shfl_xor(s1, m);
    s2 += __shfl_xor(s2, m);
    s3 += __shfl_xor(s3, m);
  }
  const float mean = s1 * (1.0f / 64.0f);
  const float var = s2 * (1.0f / 64.0f) - mean * mean;
  const float rstd = rsqrtf(var + 0.00064f);

  float4 g4 = *(const float4*)(g_f + btc);
  float4 ga4 = *(const float4*)(gamma + c);
  float4 be4 = *(const float4*)(beta + c);

  ushort4 ov;
  ov.x = f2bf(((o4.x - mean) * rstd * ga4.x + be4.x + s3 * v4.x) * g4.x);
  ov.y = f2bf(((o4.y - mean) * rstd * ga4.y + be4.y + s3 * v4.y) * g4.y);
  ov.z = f2bf(((o4.z - mean) * rstd * ga4.z + be4.z + s3 * v4.z) * g4.z);
  ov.w = f2bf(((o4.w - mean) * rstd * ga4.w + be4.w + s3 * v4.w) * g4.w);
  *(ushort4*)(yg + btc) = ov;
}

// ---------------------------------------------------------------------------
extern "C" void kernel_launch(void* const* d_in, const int* in_sizes, int n_in,
                              void* d_out, int out_size, void* d_ws, size_t ws_size,
                              hipStream_t stream)
{
  (void)in_sizes; (void)n_in; (void)out_size;
  const float* x    = (const float*)d_in[0];
  const float* x_r  = (const float*)d_in[1];
  const float* x_w  = (const float*)d_in[2];
  const float* x_k  = (const float*)d_in[3];
  const float* x_v  = (const float*)d_in[4];
  const float* x_a  = (const float*)d_in[5];
  const float* x_g  = (const float*)d_in[6];
  const float* w0   = (const float*)d_in[7];
  const float* w1   = (const float*)d_in[8];
  const float* w2   = (const float*)d_in[9];
  const float* a0   = (const float*)d_in[10];
  const float* a1   = (const float*)d_in[11];
  const float* a2   = (const float*)d_in[12];
  const float* g1   = (const float*)d_in[16];
  const float* g2   = (const float*)d_in[17];
  const float* k_k  = (const float*)d_in[18];
  const float* k_a  = (const float*)d_in[19];
  const float* r_k  = (const float*)d_in[20];
  const float* Wr   = (const float*)d_in[21];
  const float* Wk   = (const float*)d_in[22];
  const float* Wv   = (const float*)d_in[23];
  const float* Wo   = (const float*)d_in[24];
  const float* ln_g = (const float*)d_in[25];
  const float* ln_b = (const float*)d_in[26];

  float* outp = (float*)d_out;
  float* vfirst = outp + (size_t)BB * TT * CCH;

  char* ws = (char*)d_ws;
  size_t off = 0;
  auto alloc = [&](size_t bytes) -> char* {
    char* p = ws + off;
    off += (bytes + 255) & ~(size_t)255;
    return p;
  };

  unsigned short* WrT = (unsigned short*)alloc(2097152);
  unsigned short* WkT = (unsigned short*)alloc(2097152);
  unsigned short* WvT = (unsigned short*)alloc(2097152);
  unsigned short* WoT = (unsigned short*)alloc(2097152);
  unsigned short* w1T = (unsigned short*)alloc(131072);
  unsigned short* w2T = (unsigned short*)alloc(131072);
  unsigned short* a1T = (unsigned short*)alloc(131072);
  unsigned short* a2T = (unsigned short*)alloc(131072);
  unsigned short* g1T = (unsigned short*)alloc(262144);
  unsigned short* g2T = (unsigned short*)alloc(262144);
  unsigned short* xrB = (unsigned short*)alloc(8388608);
  unsigned short* xwB = (unsigned short*)alloc(8388608);
  unsigned short* xkB = (unsigned short*)alloc(8388608);
  unsigned short* xvB = (unsigned short*)alloc(8388608);
  unsigned short* xaB = (unsigned short*)alloc(8388608);
  unsigned short* xgB = (unsigned short*)alloc(8388608);
  float* r_s  = (float*)alloc(16777216);
  float* k_s  = (float*)alloc(16777216);
  float* v_s  = (float*)alloc(16777216);
  float* w_s  = (float*)alloc(16777216);   // log-decay lw
  float* aa_s = (float*)alloc(16777216);
  float* bb_s = (float*)alloc(16777216);
  float* wraw = (float*)alloc(16777216);
  float* araw = (float*)alloc(16777216);
  unsigned short* hwB = (unsigned short*)alloc(524288);
  unsigned short* haB = (unsigned short*)alloc(524288);
  unsigned short* hgB = (unsigned short*)alloc(1048576);
  unsigned short* ygB = (unsigned short*)alloc(8388608);

  // aliases for the chunked-scan stage (owners dead by then)
  float* McG = (float*)xrB;   // over xrB+xwB
  float* NcG = (float*)xkB;   // over xkB+xvB
  float* PcG = (float*)xaB;   // over xaB+xgB
  float* OlG = wraw;
  float* Sch = aa_s;
  float* o_buf = bb_s;
  float* g_f = araw;

  if (off > ws_size) return;

  dim3 blk(256);

  transpose_big4_kernel<<<dim3(16, 16, 4), blk, 0, stream>>>(Wr, Wk, Wv, Wo, WrT, WkT, WvT, WoT);
  transpose_lora_kernel<<<128, blk, 0, stream>>>(w1, w2, a1, a2, g1, g2,
                                                 w1T, w2T, a1T, a2T, g1T, g2T);

  mix_kernel<<<4096, blk, 0, stream>>>(x, x_r, x_w, x_k, x_v, x_a, x_g,
                                       xrB, xwB, xkB, xvB, xaB, xgB);

  gemm_bt_kernel<128, 4><<<dim3(32, 8), blk, 0, stream>>>(xrB, WrT, r_s, nullptr, nullptr, 4096, 1024, 1024);
  gemm_bt_kernel<128, 4><<<dim3(32, 8), blk, 0, stream>>>(xkB, WkT, k_s, nullptr, nullptr, 4096, 1024, 1024);
  gemm_bt_kernel<128, 5><<<dim3(32, 8), blk, 0, stream>>>(xvB, WvT, v_s, nullptr, vfirst, 4096, 1024, 1024);

  gemm_bt_kernel<64, 2><<<dim3(32, 1), blk, 0, stream>>>(xwB, w1T, nullptr, hwB, nullptr, 4096, 64, 1024);
  gemm_bt_kernel<128, 0><<<dim3(32, 8), blk, 0, stream>>>(hwB, w2T, wraw, nullptr, nullptr, 4096, 1024, 64);

  gemm_bt_kernel<64, 1><<<dim3(32, 1), blk, 0, stream>>>(xaB, a1T, nullptr, haB, nullptr, 4096, 64, 1024);
  gemm_bt_kernel<128, 0><<<dim3(32, 8), blk, 0, stream>>>(haB, a2T, araw, nullptr, nullptr, 4096, 1024, 64);

  postproc_kernel<<<4096, blk, 0, stream>>>(k_s, w_s, aa_s, bb_s, wraw, araw, w0, a0, k_k, k_a);

  // g path (consumes xgB BEFORE PcG overlays it)
  gemm_bt_kernel<128, 3><<<dim3(32, 1), blk, 0, stream>>>(xgB, g1T, nullptr, hgB, nullptr, 4096, 128, 1024);
  gemm_bt_kernel<128, 0><<<dim3(32, 8), blk, 0, stream>>>(hgB, g2T, g_f, nullptr, nullptr, 4096, 1024, 128);

  // chunked-DPLR scan (phase 1 on MFMA)
  constexpr int CHUNK_LDS = 12 * 64 * RS * 2 + 2 * 64 * FS * 4 + 64 * 4 + 4 * 64 * 4;
  hipFuncSetAttribute((const void*)chunk_ops_kernel,
                      hipFuncAttributeMaxDynamicSharedMemorySize, CHUNK_LDS);
  chunk_ops_kernel<<<1024, blk, CHUNK_LDS, stream>>>(r_s, w_s, k_s, v_s, aa_s, bb_s,
                                                     McG, NcG, PcG, OlG);
  chunk_scan_kernel<<<64, blk, 0, stream>>>(McG, NcG, Sch);
  chunk_out_kernel<<<1024, blk, 0, stream>>>(PcG, OlG, Sch, o_buf);

  gn_kernel<<<4096, blk, 0, stream>>>(o_buf, r_s, k_s, vfirst, g_f, ln_g, ln_b, r_k, ygB);

  gemm_bt_kernel<128, 0><<<dim3(32, 8), blk, 0, stream>>>(ygB, WoT, outp, nullptr, nullptr, 4096, 1024, 1024);
}